// Round 10
// baseline (3520.554 us; speedup 1.0000x reference)
//
#include <hip/hip_runtime.h>
#include <math.h>

// Problem constants
static constexpr int cB = 32;
static constexpr int cT = 1024;
static constexpr int cH = 128;
static constexpr int cD = 256;   // 2H
static constexpr int cN = 2048;  // H*POOL
static constexpr int cM = cB * cT; // 32768

typedef __attribute__((ext_vector_type(8))) short short8;
typedef __attribute__((ext_vector_type(4))) float f32x4;

__device__ __forceinline__ ushort f2bf(float x) {
    union { float f; unsigned u; } v; v.f = x;
    unsigned r = v.u + 0x7FFF + ((v.u >> 16) & 1);   // RNE to bf16
    return (ushort)(r >> 16);
}
__device__ __forceinline__ float bf2f(ushort h) {
    union { float f; unsigned u; } v; v.u = ((unsigned)h) << 16;
    return v.f;
}

// async global->LDS, 16B per lane, wave-uniform LDS base + lane*16
__device__ __forceinline__ void gload_lds16(const ushort* g, ushort* l) {
    __builtin_amdgcn_global_load_lds(
        (const __attribute__((address_space(1))) unsigned int*)(const void*)g,
        (__attribute__((address_space(3))) unsigned int*)(void*)l,
        16, 0, 0);
}

// ---------------------------------------------------------------------------
// SWAPPED pooled GEMM (round-9 structure, BK 128->64 for occupancy):
//   out[m][o] = max_{p<16}( sum_k X[m][k]*Wt[16o+p][k] + initv[ib][16o+p] )
// C^T via mfma(Wfrag, Xfrag): pool = 3 in-lane fmax + shfl_xor(16,32).
// Per 64-k half: stage Wt (128n x 64k hi/lo = 32KB) via gload_lds + hoist
// all X frags (16 loads) -> ONE barrier -> 2 k-steps of pure ds_read+MFMA.
// LDS 32KB/block (was 64KB): 3-4 blocks/CU resident at DIFFERENT phases so
// one block's stage drain hides under another's MFMA (round 9: 2 blocks/CU
// ran in lockstep, Occupancy 21.8%, MfmaUtil capped at 22%).
// 3-term split ah*bh+ah*bl+al*bh, fp32 acc. Block 256thr = 4 waves (2x2).
// 1-D grid 4096, bijective XCD-chunked remap. LDS swizzle: slot s of row r
// holds chunk s^(r&7) (source-side); read applies same XOR -> 2-way (free).
// ---------------------------------------------------------------------------
template<int K, bool WRITE_HL>
__global__ __launch_bounds__(256, 3)
void mfma_pool_swp(const ushort* __restrict__ Wth, const ushort* __restrict__ Wtl,
                   const ushort* __restrict__ Xh, const ushort* __restrict__ Xl,
                   const float* __restrict__ initv, int init_bstride,
                   float* __restrict__ out, ushort* __restrict__ outh,
                   ushort* __restrict__ outl)
{
    constexpr int KH = K / 64;
    __shared__ __attribute__((aligned(16))) ushort sWh[128 * 64];  // 16KB
    __shared__ __attribute__((aligned(16))) ushort sWl[128 * 64];  // 16KB

    const int tid  = threadIdx.x;
    const int wave = tid >> 6;
    const int lane = tid & 63;
    const int l15  = lane & 15;
    const int lg   = lane >> 4;
    const int wr   = wave >> 1;         // n-half
    const int wc   = wave & 1;          // m-half

    const int wg  = blockIdx.x;
    const int lin = (wg & 7) * 512 + (wg >> 3);
    const int bx  = lin & 15;           // n block (2048/128)
    const int by  = lin >> 4;           // m block (32768/128)
    const int n0  = bx * 128;
    const int m0  = by * 128;
    const size_t ibase = (size_t)(m0 >> 10) * init_bstride;

    // init values per (rf, r): n = n0 + wr*64 + rf*16 + lg*4 + r
    float ivv[4][4];
    #pragma unroll
    for (int rf = 0; rf < 4; ++rf)
        #pragma unroll
        for (int r = 0; r < 4; ++r)
            ivv[rf][r] = initv[ibase + n0 + wr * 64 + rf * 16 + lg * 4 + r];

    f32x4 acc[4][4];    // [rf(n)][cf(m)]
    #pragma unroll
    for (int rf = 0; rf < 4; ++rf)
        #pragma unroll
        for (int cf = 0; cf < 4; ++cf)
            acc[rf][cf] = (f32x4){0.f, 0.f, 0.f, 0.f};

    // staging: plane = 128 rows x 64 ushorts = 16KB = 16 x 1KB instrs;
    // instr i covers rows 8i..8i+7; lane r=lane>>3, s=lane&7 ->
    // LDS off = i*512 + lane*8 (linear); global chunk ck = s^(row&7).
    const int st_r = lane >> 3;         // 0..7
    const int st_s = lane & 7;          // 0..7

    #pragma unroll
    for (int kh = 0; kh < KH; ++kh) {
        const int kb = kh * 64;
        if (kh > 0) __syncthreads();    // all reads of previous half done

        #pragma unroll
        for (int j = 0; j < 4; ++j) {
            int i   = wave * 4 + j;             // 0..15
            int row = i * 8 + st_r;             // 0..127
            int ck  = st_s ^ (row & 7);
            size_t goff = (size_t)(n0 + row) * K + kb + ck * 8;
            gload_lds16(Wth + goff, sWh + i * 512);
            gload_lds16(Wtl + goff, sWl + i * 512);
        }
        // hoist ALL X frags of this half (4 cf x 2 ks, hi/lo = 16 loads)
        short8 xh_[8], xl_[8];
        #pragma unroll
        for (int cf = 0; cf < 4; ++cf)
            #pragma unroll
            for (int ks = 0; ks < 2; ++ks) {
                size_t off = (size_t)(m0 + wc * 64 + cf * 16 + l15) * K
                           + kb + ks * 32 + lg * 8;
                xh_[cf * 2 + ks] = *(const short8*)(Xh + off);
                xl_[cf * 2 + ks] = *(const short8*)(Xl + off);
            }
        __syncthreads();                // drains stage + X loads

        #pragma unroll
        for (int ks = 0; ks < 2; ++ks) {
            short8 w_h[4], w_l[4];
            #pragma unroll
            for (int rf = 0; rf < 4; ++rf) {
                int row  = wr * 64 + rf * 16 + l15;
                int ck2  = ks * 4 + lg;             // 0..7
                int adr  = row * 64 + ((ck2 ^ (row & 7)) * 8);
                w_h[rf] = *(const short8*)(sWh + adr);
                w_l[rf] = *(const short8*)(sWl + adr);
            }
            #pragma unroll
            for (int rf = 0; rf < 4; ++rf)
                #pragma unroll
                for (int cf = 0; cf < 4; ++cf) {
                    acc[rf][cf] = __builtin_amdgcn_mfma_f32_16x16x32_bf16(
                        w_h[rf], xh_[cf * 2 + ks], acc[rf][cf], 0, 0, 0);
                    acc[rf][cf] = __builtin_amdgcn_mfma_f32_16x16x32_bf16(
                        w_l[rf], xh_[cf * 2 + ks], acc[rf][cf], 0, 0, 0);
                    acc[rf][cf] = __builtin_amdgcn_mfma_f32_16x16x32_bf16(
                        w_h[rf], xl_[cf * 2 + ks], acc[rf][cf], 0, 0, 0);
                }
        }
    }

    // epilogue: in-lane pool over reg r + shfl over lg; write from lanes 0-15
    const int NP = 128;
    #pragma unroll
    for (int rf = 0; rf < 4; ++rf) {
        const int o2 = (n0 >> 4) + wr * 4 + rf;
        #pragma unroll
        for (int cf = 0; cf < 4; ++cf) {
            float v0 = acc[rf][cf][0] + ivv[rf][0];
            float v1 = acc[rf][cf][1] + ivv[rf][1];
            float v2 = acc[rf][cf][2] + ivv[rf][2];
            float v3 = acc[rf][cf][3] + ivv[rf][3];
            float mx = fmaxf(fmaxf(v0, v1), fmaxf(v2, v3));
            mx = fmaxf(mx, __shfl_xor(mx, 16));
            mx = fmaxf(mx, __shfl_xor(mx, 32));
            if (lane < 16) {
                int m = m0 + wc * 64 + cf * 16 + lane;
                size_t o = (size_t)m * NP + o2;
                out[o] = mx;
                if (WRITE_HL) {
                    ushort hb = f2bf(mx);
                    outh[o] = hb;
                    outl[o] = f2bf(mx - bf2f(hb));
                }
            }
        }
    }
}

// ---------------------------------------------------------------------------
// A1 GEMM (no pool), K=256: out[m][n] = sum_k U[m][k]*W1t[n][k], fp32 out.
// Same BK=64 hoisted structure; unswapped (coalesced 268MB writes).
// ---------------------------------------------------------------------------
__global__ __launch_bounds__(256, 3)
void mfma_gemm_a1(const ushort* __restrict__ Uh, const ushort* __restrict__ Ul,
                  const ushort* __restrict__ Bth, const ushort* __restrict__ Btl,
                  float* __restrict__ out)
{
    constexpr int K = 256;
    __shared__ __attribute__((aligned(16))) ushort sBh[128 * 64];
    __shared__ __attribute__((aligned(16))) ushort sBl[128 * 64];

    const int tid  = threadIdx.x;
    const int wave = tid >> 6;
    const int lane = tid & 63;
    const int l15  = lane & 15;
    const int lg   = lane >> 4;
    const int wr   = wave >> 1;         // m-half
    const int wc   = wave & 1;          // n-half

    const int wg  = blockIdx.x;
    const int lin = (wg & 7) * 512 + (wg >> 3);
    const int bx  = lin & 15;
    const int by  = lin >> 4;
    const int n0  = bx * 128;
    const int m0  = by * 128;

    f32x4 acc[4][4];    // [mf][nf]
    #pragma unroll
    for (int mf = 0; mf < 4; ++mf)
        #pragma unroll
        for (int nf = 0; nf < 4; ++nf)
            acc[mf][nf] = (f32x4){0.f, 0.f, 0.f, 0.f};

    const int st_r = lane >> 3;
    const int st_s = lane & 7;

    #pragma unroll
    for (int kh = 0; kh < 4; ++kh) {
        const int kb = kh * 64;
        if (kh > 0) __syncthreads();

        #pragma unroll
        for (int j = 0; j < 4; ++j) {
            int i   = wave * 4 + j;
            int row = i * 8 + st_r;
            int ck  = st_s ^ (row & 7);
            size_t goff = (size_t)(n0 + row) * K + kb + ck * 8;
            gload_lds16(Bth + goff, sBh + i * 512);
            gload_lds16(Btl + goff, sBl + i * 512);
        }
        short8 ph[8], pl[8];
        #pragma unroll
        for (int mf = 0; mf < 4; ++mf)
            #pragma unroll
            for (int ks = 0; ks < 2; ++ks) {
                size_t off = (size_t)(m0 + wr * 64 + mf * 16 + l15) * K
                           + kb + ks * 32 + lg * 8;
                ph[mf * 2 + ks] = *(const short8*)(Uh + off);
                pl[mf * 2 + ks] = *(const short8*)(Ul + off);
            }
        __syncthreads();

        #pragma unroll
        for (int ks = 0; ks < 2; ++ks) {
            short8 b_h[4], b_l[4];
            #pragma unroll
            for (int nf = 0; nf < 4; ++nf) {
                int row  = wc * 64 + nf * 16 + l15;
                int ck2  = ks * 4 + lg;
                int adr  = row * 64 + ((ck2 ^ (row & 7)) * 8);
                b_h[nf] = *(const short8*)(sBh + adr);
                b_l[nf] = *(const short8*)(sBl + adr);
            }
            #pragma unroll
            for (int mf = 0; mf < 4; ++mf)
                #pragma unroll
                for (int nf = 0; nf < 4; ++nf) {
                    acc[mf][nf] = __builtin_amdgcn_mfma_f32_16x16x32_bf16(
                        ph[mf * 2 + ks], b_h[nf], acc[mf][nf], 0, 0, 0);
                    acc[mf][nf] = __builtin_amdgcn_mfma_f32_16x16x32_bf16(
                        ph[mf * 2 + ks], b_l[nf], acc[mf][nf], 0, 0, 0);
                    acc[mf][nf] = __builtin_amdgcn_mfma_f32_16x16x32_bf16(
                        pl[mf * 2 + ks], b_h[nf], acc[mf][nf], 0, 0, 0);
                }
        }
    }

    #pragma unroll
    for (int mf = 0; mf < 4; ++mf)
        #pragma unroll
        for (int nf = 0; nf < 4; ++nf) {
            int col = n0 + wc * 64 + nf * 16 + l15;
            #pragma unroll
            for (int r = 0; r < 4; ++r) {
                int row = m0 + wr * 64 + mf * 16 + lg * 4 + r;
                out[(size_t)row * cN + col] = acc[mf][nf][r];
            }
        }
}

// ---------------------------------------------------------------------------
// m1[m][o] = max_p( A1[m][o*16+p] + rterm[b][o*16+p] ), also emits bf16 hi/lo
// ---------------------------------------------------------------------------
__global__ void m1_from_a1_kernel(const float* __restrict__ A1,
                                  const float* __restrict__ rterm,
                                  float* __restrict__ m1,
                                  ushort* __restrict__ m1h,
                                  ushort* __restrict__ m1l)
{
    int idx = blockIdx.x * 256 + threadIdx.x;   // [0, 32768*128)
    int m = idx >> 7;
    int o = idx & 127;
    int b = m >> 10;
    const float4* a  = (const float4*)(A1 + (size_t)m * cN + o * 16);
    const float4* rt = (const float4*)(rterm + (size_t)b * cN + o * 16);
    float mx = -3.4e38f;
    #pragma unroll
    for (int q = 0; q < 4; ++q) {
        float4 av = a[q];
        float4 rv = rt[q];
        mx = fmaxf(mx, fmaxf(fmaxf(av.x + rv.x, av.y + rv.y),
                             fmaxf(av.z + rv.z, av.w + rv.w)));
    }
    m1[idx] = mx;
    ushort hb = f2bf(mx);
    m1h[idx] = hb;
    m1l[idx] = f2bf(mx - bf2f(hb));
}

// ---------------------------------------------------------------------------
// Weight transpose + bf16 split: W[K x N] row-major -> Wt hi/lo [N][K]
// ---------------------------------------------------------------------------
__global__ void wsplit_kernel(const float* __restrict__ W, int K, int N,
                              ushort* __restrict__ th, ushort* __restrict__ tl)
{
    int idx = blockIdx.x * 256 + threadIdx.x;
    if (idx >= K * N) return;
    int k = idx / N, n = idx - k * N;      // coalesced read
    float x = W[idx];
    ushort h = f2bf(x);
    th[(size_t)n * K + k] = h;
    tl[(size_t)n * K + k] = f2bf(x - bf2f(h));
}

// ---------------------------------------------------------------------------
// U split: U fp32 [M][256] -> Uh/Ul bf16 same layout
// ---------------------------------------------------------------------------
__global__ void usplit_kernel(const float* __restrict__ U,
                              ushort* __restrict__ uh, ushort* __restrict__ ul)
{
    int idx = blockIdx.x * 256 + threadIdx.x;   // cM*cD threads
    float x = U[idx];
    ushort h = f2bf(x);
    uh[idx] = h;
    ul[idx] = f2bf(x - bf2f(h));
}

// ---------------------------------------------------------------------------
// r[b][j] = tanh( concat([h,us,ue])[b] . WDw[:,j] + WDb[j] )
// ---------------------------------------------------------------------------
__global__ void r_kernel(const float* __restrict__ h, const float* __restrict__ us,
                         const float* __restrict__ ue,
                         const float* __restrict__ WDw, const float* __restrict__ WDb,
                         float* __restrict__ r)
{
    int b = blockIdx.x;
    int j = threadIdx.x;  // 128 threads
    __shared__ float x[640];
    x[j]       = h[b * cH + j];
    x[128 + j] = us[b * cD + j];
    x[256 + j] = us[b * cD + 128 + j];
    x[384 + j] = ue[b * cD + j];
    x[512 + j] = ue[b * cD + 128 + j];
    __syncthreads();
    float s = WDb[j];
    for (int k = 0; k < 640; ++k) s = fmaf(x[k], WDw[(size_t)k * cH + j], s);
    r[b * cH + j] = tanhf(s);
}

// ---------------------------------------------------------------------------
// rterm[b][n] = r[b] . W1r[:,n] + W1b[n]    (W1r = rows 256..383 of W1w)
// ---------------------------------------------------------------------------
__global__ void rterm_kernel(const float* __restrict__ r, const float* __restrict__ W1r,
                             const float* __restrict__ W1b, float* __restrict__ rterm)
{
    int b = blockIdx.y;
    int n = blockIdx.x * 256 + threadIdx.x;  // grid (8,32)
    __shared__ float rs[128];
    if (threadIdx.x < 128) rs[threadIdx.x] = r[b * cH + threadIdx.x];
    __syncthreads();
    float s = W1b[n];
    for (int k = 0; k < 128; ++k) s = fmaf(rs[k], W1r[(size_t)k * cN + n], s);
    rterm[(size_t)b * cN + n] = s;
}

// ---------------------------------------------------------------------------
// score[m] = max_p( concat([m1,m2])[m] . W3w[:,p] + W3b[p] ) -> ent region
// ---------------------------------------------------------------------------
__global__ __launch_bounds__(256)
void score_kernel(const float* __restrict__ m1, const float* __restrict__ m2,
                  const float* __restrict__ W3w, const float* __restrict__ W3b,
                  float* __restrict__ ent)
{
    __shared__ float xs[16][257];
    __shared__ float wsh[256 * 16];
    int tid = threadIdx.x;
    int m0 = blockIdx.x * 16;
    #pragma unroll
    for (int q = 0; q < 16; ++q) wsh[tid + q * 256] = W3w[tid + q * 256];
    #pragma unroll
    for (int q = 0; q < 8; ++q) {
        int f = tid + q * 256;
        int rl = f >> 7, col = f & 127;
        xs[rl][col]       = m1[(size_t)(m0 + rl) * cH + col];
        xs[rl][128 + col] = m2[(size_t)(m0 + rl) * cH + col];
    }
    __syncthreads();
    int rl = tid >> 4, p = tid & 15;
    float s = W3b[p];
    for (int k = 0; k < 256; ++k) s = fmaf(xs[rl][k], wsh[k * 16 + p], s);
    #pragma unroll
    for (int off = 8; off; off >>= 1) s = fmaxf(s, __shfl_xor(s, off));
    if (p == 0) ent[m0 + rl] = s;
}

// ---------------------------------------------------------------------------
// argmax over T per batch (first-occurrence ties), write float index,
// gather U row into us/ue
// ---------------------------------------------------------------------------
__global__ void argmax_kernel(const float* __restrict__ sc, const float* __restrict__ U,
                              float* __restrict__ uvec, float* __restrict__ outidx)
{
    int b = blockIdx.x;
    int tid = threadIdx.x;  // 256
    float bv = -3.4e38f;
    int bi = 0x7fffffff;
    for (int t = tid; t < cT; t += 256) {
        float v = sc[b * cT + t];
        if (v > bv || (v == bv && t < bi)) { bv = v; bi = t; }
    }
    __shared__ float vs[256];
    __shared__ int   is[256];
    vs[tid] = bv; is[tid] = bi;
    __syncthreads();
    for (int s = 128; s > 0; s >>= 1) {
        if (tid < s) {
            if (vs[tid + s] > vs[tid] ||
                (vs[tid + s] == vs[tid] && is[tid + s] < is[tid])) {
                vs[tid] = vs[tid + s];
                is[tid] = is[tid + s];
            }
        }
        __syncthreads();
    }
    int best = is[0];
    if (tid == 0) outidx[b] = (float)best;
    uvec[b * cD + tid % cD] = U[((size_t)b * cT + best) * cD + (tid % cD)];
}

// ---------------------------------------------------------------------------
// LSTM cell
// ---------------------------------------------------------------------------
__global__ void lstm_kernel(const float* __restrict__ us, const float* __restrict__ ue,
                            float* __restrict__ h, float* __restrict__ c,
                            const float* __restrict__ wih, const float* __restrict__ whh,
                            const float* __restrict__ bih, const float* __restrict__ bhh)
{
    int b = blockIdx.x;
    int j = threadIdx.x;  // 128
    __shared__ float x[512];
    __shared__ float hh[128];
    x[j]       = us[b * cD + j];
    x[128 + j] = us[b * cD + 128 + j];
    x[256 + j] = ue[b * cD + j];
    x[384 + j] = ue[b * cD + 128 + j];
    hh[j] = h[b * cH + j];
    __syncthreads();
    float g4[4];
    #pragma unroll
    for (int gi = 0; gi < 4; ++gi) {
        int row = gi * 128 + j;
        float s = bih[row] + bhh[row];
        const float* wr = wih + (size_t)row * 512;
        for (int k = 0; k < 512; ++k) s = fmaf(x[k], wr[k], s);
        const float* wr2 = whh + (size_t)row * 128;
        for (int k = 0; k < 128; ++k) s = fmaf(hh[k], wr2[k], s);
        g4[gi] = s;
    }
    float i_ = 1.f / (1.f + expf(-g4[0]));
    float f_ = 1.f / (1.f + expf(-g4[1]));
    float g_ = tanhf(g4[2]);
    float o_ = 1.f / (1.f + expf(-g4[3]));
    float c2 = f_ * c[b * cH + j] + i_ * g_;
    float h2 = o_ * tanhf(c2);
    c[b * cH + j] = c2;
    h[b * cH + j] = h2;
}

__global__ void init_kernel(const float* __restrict__ U, float* __restrict__ us,
                            float* __restrict__ ue, float* __restrict__ h,
                            float* __restrict__ c)
{
    int i = blockIdx.x * 256 + threadIdx.x;  // 8192 threads
    if (i < cB * cD) {
        int b = i >> 8, d = i & 255;
        us[i] = U[((size_t)b * cT + 0) * cD + d];
        ue[i] = U[((size_t)b * cT + 1) * cD + d];
    }
    if (i < cB * cH) { h[i] = 0.f; c[i] = 0.f; }
}

// ---------------------------------------------------------------------------
extern "C" void kernel_launch(void* const* d_in, const int* in_sizes, int n_in,
                              void* d_out, int out_size, void* d_ws, size_t ws_size,
                              hipStream_t stream)
{
    const float* U = (const float*)d_in[0];
    const float* WD_w[2] = {(const float*)d_in[1], (const float*)d_in[9]};
    const float* WD_b[2] = {(const float*)d_in[2], (const float*)d_in[10]};
    const float* W1_w[2] = {(const float*)d_in[3], (const float*)d_in[11]};
    const float* W1_b[2] = {(const float*)d_in[4], (const float*)d_in[12]};
    const float* W2_w[2] = {(const float*)d_in[5], (const float*)d_in[13]};
    const float* W2_b[2] = {(const float*)d_in[6], (const float*)d_in[14]};
    const float* W3_w[2] = {(const float*)d_in[7], (const float*)d_in[15]};
    const float* W3_b[2] = {(const float*)d_in[8], (const float*)d_in[16]};
    const float* wih = (const float*)d_in[17];
    const float* whh = (const float*)d_in[18];
    const float* bih = (const float*)d_in[19];
    const float* bhh = (const float*)d_in[20];

    float* ws = (float*)d_ws;
    float* m1 = ws;                               // 4M floats
    float* m2 = m1 + (size_t)cM * cH;             // 4M
    float* us = m2 + (size_t)cM * cH;
    float* ue = us + cB * cD;
    float* h  = ue + cB * cD;
    float* c  = h + cB * cH;
    float* r  = c + cB * cH;
    float* rterm = r + cB * cH;                   // 64K
    float* cur = rterm + (size_t)cB * cN;

    ushort* m1h = (ushort*)cur;                   cur += (size_t)cM * cH / 2;
    ushort* m1l = (ushort*)cur;                   cur += (size_t)cM * cH / 2;
    ushort* Uh  = (ushort*)cur;                   cur += (size_t)cM * cD / 2;
    ushort* Ul  = (ushort*)cur;                   cur += (size_t)cM * cD / 2;
    ushort* W1th[2], *W1tl[2], *W2th[2], *W2tl[2];
    for (int sd = 0; sd < 2; ++sd) {
        W1th[sd] = (ushort*)cur; cur += (size_t)cN * cD / 2;   // [2048][256]
        W1tl[sd] = (ushort*)cur; cur += (size_t)cN * cD / 2;
        W2th[sd] = (ushort*)cur; cur += (size_t)cN * cH / 2;   // [2048][128]
        W2tl[sd] = (ushort*)cur; cur += (size_t)cN * cH / 2;
    }
    float* A1[2];
    A1[0] = cur;
    A1[1] = A1[0] + (size_t)cM * cN;              // 64M floats each
    size_t need = (size_t)(A1[1] - ws) + (size_t)cM * cN;
    bool pre = ws_size >= need * sizeof(float);

    float* outf = (float*)d_out;

    init_kernel<<<32, 256, 0, stream>>>(U, us, ue, h, c);
    usplit_kernel<<<(cM * cD) / 256, 256, 0, stream>>>(U, Uh, Ul);
    for (int sd = 0; sd < 2; ++sd) {
        wsplit_kernel<<<(cD * cN) / 256, 256, 0, stream>>>(
            W1_w[sd], cD, cN, W1th[sd], W1tl[sd]);     // first 256 rows of W1
        wsplit_kernel<<<(cH * cN) / 256, 256, 0, stream>>>(
            W2_w[sd], cH, cN, W2th[sd], W2tl[sd]);
    }

    const int ggrid = (cN / 128) * (cM / 128);   // 4096, 1-D (XCD swizzle inside)
    if (pre) {
        // A1 = U @ W1w[0:256,:] once per weight set (constant across iters)
        for (int sd = 0; sd < 2; ++sd)
            mfma_gemm_a1<<<ggrid, 256, 0, stream>>>(
                Uh, Ul, W1th[sd], W1tl[sd], A1[sd]);
    }

    for (int it = 0; it < 4; ++it) {
        for (int sd = 0; sd < 2; ++sd) {
            r_kernel<<<32, 128, 0, stream>>>(h, us, ue, WD_w[sd], WD_b[sd], r);
            rterm_kernel<<<dim3(8, 32), 256, 0, stream>>>(
                r, W1_w[sd] + (size_t)256 * cN, W1_b[sd], rterm);
            if (pre) {
                m1_from_a1_kernel<<<16384, 256, 0, stream>>>(
                    A1[sd], rterm, m1, m1h, m1l);
            } else {
                mfma_pool_swp<256, true><<<ggrid, 256, 0, stream>>>(
                    W1th[sd], W1tl[sd], Uh, Ul, rterm, cN, m1, m1h, m1l);
            }
            // m2 = pool(m1 @ W2 + b2) -> fp32 (swapped orientation)
            mfma_pool_swp<128, false><<<ggrid, 256, 0, stream>>>(
                W2th[sd], W2tl[sd], m1h, m1l, W2_b[sd], 0, m2, nullptr, nullptr);
            float* ent = outf + 64 + (size_t)(it * 2 + sd) * cB * cT;
            score_kernel<<<2048, 256, 0, stream>>>(m1, m2, W3_w[sd], W3_b[sd], ent);
            argmax_kernel<<<32, 256, 0, stream>>>(ent, U, sd ? ue : us,
                                                  outf + (sd ? 32 : 0));
        }
        lstm_kernel<<<32, 128, 0, stream>>>(us, ue, h, c, wih, whh, bih, bhh);
    }
}

// Round 11
// 3197.820 us; speedup vs baseline: 1.1009x; 1.1009x over previous
//
#include <hip/hip_runtime.h>
#include <math.h>

// Problem constants
static constexpr int cB = 32;
static constexpr int cT = 1024;
static constexpr int cH = 128;
static constexpr int cD = 256;   // 2H
static constexpr int cN = 2048;  // H*POOL
static constexpr int cM = cB * cT; // 32768

typedef __attribute__((ext_vector_type(8))) short short8;
typedef __attribute__((ext_vector_type(4))) float f32x4;

__device__ __forceinline__ ushort f2bf(float x) {
    union { float f; unsigned u; } v; v.f = x;
    unsigned r = v.u + 0x7FFF + ((v.u >> 16) & 1);   // RNE to bf16
    return (ushort)(r >> 16);
}
__device__ __forceinline__ float bf2f(ushort h) {
    union { float f; unsigned u; } v; v.u = ((unsigned)h) << 16;
    return v.f;
}

// async global->LDS, 16B per lane, wave-uniform LDS base + lane*16
__device__ __forceinline__ void gload_lds16(const ushort* g, ushort* l) {
    __builtin_amdgcn_global_load_lds(
        (const __attribute__((address_space(1))) unsigned int*)(const void*)g,
        (__attribute__((address_space(3))) unsigned int*)(void*)l,
        16, 0, 0);
}

// ---------------------------------------------------------------------------
// WEIGHT-STATIONARY pooled m2 GEMM (K=128), no LDS, no barriers:
//   out[m][o] = max_{p<16}( sum_k X[m][k]*Wt[16o+p][k] + bias[16o+p] )
// One block per CU (grid 256 = 16 m-groups x 16 n-blocks). Each wave loads
// its ENTIRE W fragment set ONCE into registers (4rf x 4ks x hi/lo = 128
// VGPR), then streams 16 m-subtiles {32 X loads -> 192 MFMA -> pool epi}
// with no synchronization — compiler pipelines X loads across subtiles.
// Swapped orientation mfma(W,X): D row=n col=m -> pool = 3 in-lane fmax +
// shfl_xor(16,32). 3-term split wh*xh+wl*xh+wh*xl, fp32 acc.
// XCD-chunked lin: each XCD's hot set = 2 m-group X slices (2MB) + W2 (1MB)
// < 4MB L2. (Round 9: per-block 64KB restage + lockstep barriers -> 197us,
// MfmaUtil 22%; round 10 (256,3) spilled: VGPR 84, scratch 400MB.)
// ---------------------------------------------------------------------------
__global__ __launch_bounds__(256, 1)
void mfma_pool_ws(const ushort* __restrict__ Wth, const ushort* __restrict__ Wtl,
                  const ushort* __restrict__ Xh, const ushort* __restrict__ Xl,
                  const float* __restrict__ bias, float* __restrict__ out)
{
    constexpr int K = 128;
    const int lane = threadIdx.x & 63;
    const int wave = threadIdx.x >> 6;
    const int l15  = lane & 15;
    const int lg   = lane >> 4;
    const int wr   = wave >> 1;         // n-half
    const int wc   = wave & 1;          // m-half

    const int wg  = blockIdx.x;                 // grid 256
    const int lin = (wg & 7) * 32 + (wg >> 3);  // XCD-chunked, bijective
    const int bx  = lin & 15;                   // n block (128 cols)
    const int by  = lin >> 4;                   // m group (2048 rows)
    const int n0  = bx * 128;
    const int mg0 = by * 2048;

    // ---- W fragments: resident for the whole block ------------------------
    short8 w_h[4][4], w_l[4][4];        // [rf][ks] = 128 VGPR
    #pragma unroll
    for (int rf = 0; rf < 4; ++rf)
        #pragma unroll
        for (int ks = 0; ks < 4; ++ks) {
            size_t off = (size_t)(n0 + wr * 64 + rf * 16 + l15) * K
                       + ks * 32 + lg * 8;
            w_h[rf][ks] = *(const short8*)(Wth + off);
            w_l[rf][ks] = *(const short8*)(Wtl + off);
        }
    // bias per (rf, reg r): n = n0 + wr*64 + rf*16 + lg*4 + r
    float ivv[4][4];
    #pragma unroll
    for (int rf = 0; rf < 4; ++rf)
        #pragma unroll
        for (int r = 0; r < 4; ++r)
            ivv[rf][r] = bias[n0 + wr * 64 + rf * 16 + lg * 4 + r];

    const int NP = 128;
    #pragma unroll 1
    for (int sub = 0; sub < 16; ++sub) {
        const int m0 = mg0 + sub * 128;

        short8 xh_[4][4], xl_[4][4];    // [cf][ks]
        #pragma unroll
        for (int cf = 0; cf < 4; ++cf)
            #pragma unroll
            for (int ks = 0; ks < 4; ++ks) {
                size_t off = (size_t)(m0 + wc * 64 + cf * 16 + l15) * K
                           + ks * 32 + lg * 8;
                xh_[cf][ks] = *(const short8*)(Xh + off);
                xl_[cf][ks] = *(const short8*)(Xl + off);
            }

        f32x4 acc[4][4];    // [rf][cf]
        #pragma unroll
        for (int rf = 0; rf < 4; ++rf)
            #pragma unroll
            for (int cf = 0; cf < 4; ++cf)
                acc[rf][cf] = (f32x4){0.f, 0.f, 0.f, 0.f};

        #pragma unroll
        for (int ks = 0; ks < 4; ++ks)
            #pragma unroll
            for (int rf = 0; rf < 4; ++rf)
                #pragma unroll
                for (int cf = 0; cf < 4; ++cf) {
                    acc[rf][cf] = __builtin_amdgcn_mfma_f32_16x16x32_bf16(
                        w_h[rf][ks], xh_[cf][ks], acc[rf][cf], 0, 0, 0);
                    acc[rf][cf] = __builtin_amdgcn_mfma_f32_16x16x32_bf16(
                        w_l[rf][ks], xh_[cf][ks], acc[rf][cf], 0, 0, 0);
                    acc[rf][cf] = __builtin_amdgcn_mfma_f32_16x16x32_bf16(
                        w_h[rf][ks], xl_[cf][ks], acc[rf][cf], 0, 0, 0);
                }

        // pool + write
        #pragma unroll
        for (int rf = 0; rf < 4; ++rf) {
            const int o2 = (n0 >> 4) + wr * 4 + rf;
            #pragma unroll
            for (int cf = 0; cf < 4; ++cf) {
                float v0 = acc[rf][cf][0] + ivv[rf][0];
                float v1 = acc[rf][cf][1] + ivv[rf][1];
                float v2 = acc[rf][cf][2] + ivv[rf][2];
                float v3 = acc[rf][cf][3] + ivv[rf][3];
                float mx = fmaxf(fmaxf(v0, v1), fmaxf(v2, v3));
                mx = fmaxf(mx, __shfl_xor(mx, 16));
                mx = fmaxf(mx, __shfl_xor(mx, 32));
                if (lane < 16) {
                    int m = m0 + wc * 64 + cf * 16 + lane;
                    out[(size_t)m * NP + o2] = mx;
                }
            }
        }
    }
}

// ---------------------------------------------------------------------------
// WEIGHT-STATIONARY A1 GEMM (K=256, no pool): out[m][n] = U[m]:W1t[n], fp32.
// n-block = 64 so the wave's W frags (2nf x 8ks x hi/lo = 128 VGPR) stay
// resident. Grid 256 (32 n-blocks x 8 m-groups of 4096 rows = 32 subtiles).
// X loads chunked per-mf (64 VGPR live) to bound pressure. Unswapped
// orientation (coalesced 268MB writes). No LDS, no barriers.
// ---------------------------------------------------------------------------
__global__ __launch_bounds__(256, 1)
void mfma_a1_ws(const ushort* __restrict__ Uh, const ushort* __restrict__ Ul,
                const ushort* __restrict__ Bth, const ushort* __restrict__ Btl,
                float* __restrict__ out)
{
    constexpr int K = 256;
    const int lane = threadIdx.x & 63;
    const int wave = threadIdx.x >> 6;
    const int l15  = lane & 15;
    const int lg   = lane >> 4;
    const int wr   = wave >> 1;         // m-half
    const int wc   = wave & 1;          // n-half

    const int wg  = blockIdx.x;                 // grid 256
    const int lin = (wg & 7) * 32 + (wg >> 3);
    const int bx  = lin & 31;                   // n block (64 cols)
    const int by  = lin >> 5;                   // m group (4096 rows)
    const int n0  = bx * 64;
    const int mg0 = by * 4096;

    short8 b_h[2][8], b_l[2][8];        // [nf][ks] = 128 VGPR, resident
    #pragma unroll
    for (int nf = 0; nf < 2; ++nf)
        #pragma unroll
        for (int ks = 0; ks < 8; ++ks) {
            size_t off = (size_t)(n0 + wc * 32 + nf * 16 + l15) * K
                       + ks * 32 + lg * 8;
            b_h[nf][ks] = *(const short8*)(Bth + off);
            b_l[nf][ks] = *(const short8*)(Btl + off);
        }

    #pragma unroll 1
    for (int sub = 0; sub < 32; ++sub) {
        const int m0 = mg0 + sub * 128;
        f32x4 acc[4][2];    // [mf][nf]
        #pragma unroll
        for (int mf = 0; mf < 4; ++mf)
            #pragma unroll
            for (int nf = 0; nf < 2; ++nf)
                acc[mf][nf] = (f32x4){0.f, 0.f, 0.f, 0.f};

        #pragma unroll
        for (int mf = 0; mf < 4; ++mf) {
            short8 uh_[8], ul_[8];      // this mf's K-row, 64 VGPR
            #pragma unroll
            for (int ks = 0; ks < 8; ++ks) {
                size_t off = (size_t)(m0 + wr * 64 + mf * 16 + l15) * K
                           + ks * 32 + lg * 8;
                uh_[ks] = *(const short8*)(Uh + off);
                ul_[ks] = *(const short8*)(Ul + off);
            }
            #pragma unroll
            for (int ks = 0; ks < 8; ++ks)
                #pragma unroll
                for (int nf = 0; nf < 2; ++nf) {
                    acc[mf][nf] = __builtin_amdgcn_mfma_f32_16x16x32_bf16(
                        uh_[ks], b_h[nf][ks], acc[mf][nf], 0, 0, 0);
                    acc[mf][nf] = __builtin_amdgcn_mfma_f32_16x16x32_bf16(
                        uh_[ks], b_l[nf][ks], acc[mf][nf], 0, 0, 0);
                    acc[mf][nf] = __builtin_amdgcn_mfma_f32_16x16x32_bf16(
                        ul_[ks], b_h[nf][ks], acc[mf][nf], 0, 0, 0);
                }
        }

        #pragma unroll
        for (int mf = 0; mf < 4; ++mf)
            #pragma unroll
            for (int nf = 0; nf < 2; ++nf) {
                int col = n0 + wc * 32 + nf * 16 + l15;
                #pragma unroll
                for (int r = 0; r < 4; ++r) {
                    int row = m0 + wr * 64 + mf * 16 + lg * 4 + r;
                    out[(size_t)row * cN + col] = acc[mf][nf][r];
                }
            }
    }
}

// ---------------------------------------------------------------------------
// Round-9 verified pooled GEMM (LDS-staged, (256,2)) — non-pre FALLBACK only.
// ---------------------------------------------------------------------------
template<int K, bool WRITE_HL>
__global__ __launch_bounds__(256, 2)
void mfma_pool_swp(const ushort* __restrict__ Wth, const ushort* __restrict__ Wtl,
                   const ushort* __restrict__ Xh, const ushort* __restrict__ Xl,
                   const float* __restrict__ initv, int init_bstride,
                   float* __restrict__ out, ushort* __restrict__ outh,
                   ushort* __restrict__ outl)
{
    constexpr int KH = K / 128;
    __shared__ __attribute__((aligned(16))) ushort sWh[128 * 128];
    __shared__ __attribute__((aligned(16))) ushort sWl[128 * 128];

    const int tid  = threadIdx.x;
    const int wave = tid >> 6;
    const int lane = tid & 63;
    const int l15  = lane & 15;
    const int lg   = lane >> 4;
    const int wr   = wave >> 1;
    const int wc   = wave & 1;

    const int wg  = blockIdx.x;
    const int lin = (wg & 7) * 512 + (wg >> 3);
    const int bx  = lin & 15;
    const int by  = lin >> 4;
    const int n0  = bx * 128;
    const int m0  = by * 128;
    const size_t ibase = (size_t)(m0 >> 10) * init_bstride;

    float ivv[4][4];
    #pragma unroll
    for (int rf = 0; rf < 4; ++rf)
        #pragma unroll
        for (int r = 0; r < 4; ++r)
            ivv[rf][r] = initv[ibase + n0 + wr * 64 + rf * 16 + lg * 4 + r];

    f32x4 acc[4][4];
    #pragma unroll
    for (int rf = 0; rf < 4; ++rf)
        #pragma unroll
        for (int cf = 0; cf < 4; ++cf)
            acc[rf][cf] = (f32x4){0.f, 0.f, 0.f, 0.f};

    const int st_row_lo = lane >> 4;
    const int st_slot   = lane & 15;

    #pragma unroll
    for (int kh = 0; kh < KH; ++kh) {
        const int kb = kh * 128;
        if (kh > 0) __syncthreads();

        #pragma unroll
        for (int j = 0; j < 8; ++j) {
            int i   = wave * 8 + j;
            int row = i * 4 + st_row_lo;
            int ck  = st_slot ^ (row & 7);
            size_t goff = (size_t)(n0 + row) * K + kb + ck * 8;
            gload_lds16(Wth + goff, sWh + i * 512);
            gload_lds16(Wtl + goff, sWl + i * 512);
        }
        short8 xh_[16], xl_[16];
        #pragma unroll
        for (int cf = 0; cf < 4; ++cf)
            #pragma unroll
            for (int ks = 0; ks < 4; ++ks) {
                size_t off = (size_t)(m0 + wc * 64 + cf * 16 + l15) * K
                           + kb + ks * 32 + lg * 8;
                xh_[cf * 4 + ks] = *(const short8*)(Xh + off);
                xl_[cf * 4 + ks] = *(const short8*)(Xl + off);
            }
        __syncthreads();

        #pragma unroll
        for (int ks = 0; ks < 4; ++ks) {
            short8 w_h[4], w_l[4];
            #pragma unroll
            for (int rf = 0; rf < 4; ++rf) {
                int row  = wr * 64 + rf * 16 + l15;
                int ck2  = ks * 4 + lg;
                int adr  = row * 128 + ((ck2 ^ (row & 7)) * 8);
                w_h[rf] = *(const short8*)(sWh + adr);
                w_l[rf] = *(const short8*)(sWl + adr);
            }
            #pragma unroll
            for (int rf = 0; rf < 4; ++rf)
                #pragma unroll
                for (int cf = 0; cf < 4; ++cf) {
                    acc[rf][cf] = __builtin_amdgcn_mfma_f32_16x16x32_bf16(
                        w_h[rf], xh_[cf * 4 + ks], acc[rf][cf], 0, 0, 0);
                    acc[rf][cf] = __builtin_amdgcn_mfma_f32_16x16x32_bf16(
                        w_l[rf], xh_[cf * 4 + ks], acc[rf][cf], 0, 0, 0);
                    acc[rf][cf] = __builtin_amdgcn_mfma_f32_16x16x32_bf16(
                        w_h[rf], xl_[cf * 4 + ks], acc[rf][cf], 0, 0, 0);
                }
        }
    }

    const int NP = 128;
    #pragma unroll
    for (int rf = 0; rf < 4; ++rf) {
        const int o2 = (n0 >> 4) + wr * 4 + rf;
        #pragma unroll
        for (int cf = 0; cf < 4; ++cf) {
            float v0 = acc[rf][cf][0] + ivv[rf][0];
            float v1 = acc[rf][cf][1] + ivv[rf][1];
            float v2 = acc[rf][cf][2] + ivv[rf][2];
            float v3 = acc[rf][cf][3] + ivv[rf][3];
            float mx = fmaxf(fmaxf(v0, v1), fmaxf(v2, v3));
            mx = fmaxf(mx, __shfl_xor(mx, 16));
            mx = fmaxf(mx, __shfl_xor(mx, 32));
            if (lane < 16) {
                int m = m0 + wc * 64 + cf * 16 + lane;
                size_t o = (size_t)m * NP + o2;
                out[o] = mx;
                if (WRITE_HL) {
                    ushort hb = f2bf(mx);
                    outh[o] = hb;
                    outl[o] = f2bf(mx - bf2f(hb));
                }
            }
        }
    }
}

// ---------------------------------------------------------------------------
// m1[m][o] = max_p( A1[m][o*16+p] + rterm[b][o*16+p] ), also emits bf16 hi/lo
// ---------------------------------------------------------------------------
__global__ void m1_from_a1_kernel(const float* __restrict__ A1,
                                  const float* __restrict__ rterm,
                                  float* __restrict__ m1,
                                  ushort* __restrict__ m1h,
                                  ushort* __restrict__ m1l)
{
    int idx = blockIdx.x * 256 + threadIdx.x;   // [0, 32768*128)
    int m = idx >> 7;
    int o = idx & 127;
    int b = m >> 10;
    const float4* a  = (const float4*)(A1 + (size_t)m * cN + o * 16);
    const float4* rt = (const float4*)(rterm + (size_t)b * cN + o * 16);
    float mx = -3.4e38f;
    #pragma unroll
    for (int q = 0; q < 4; ++q) {
        float4 av = a[q];
        float4 rv = rt[q];
        mx = fmaxf(mx, fmaxf(fmaxf(av.x + rv.x, av.y + rv.y),
                             fmaxf(av.z + rv.z, av.w + rv.w)));
    }
    m1[idx] = mx;
    ushort hb = f2bf(mx);
    m1h[idx] = hb;
    m1l[idx] = f2bf(mx - bf2f(hb));
}

// ---------------------------------------------------------------------------
// Weight transpose + bf16 split: W[K x N] row-major -> Wt hi/lo [N][K]
// ---------------------------------------------------------------------------
__global__ void wsplit_kernel(const float* __restrict__ W, int K, int N,
                              ushort* __restrict__ th, ushort* __restrict__ tl)
{
    int idx = blockIdx.x * 256 + threadIdx.x;
    if (idx >= K * N) return;
    int k = idx / N, n = idx - k * N;      // coalesced read
    float x = W[idx];
    ushort h = f2bf(x);
    th[(size_t)n * K + k] = h;
    tl[(size_t)n * K + k] = f2bf(x - bf2f(h));
}

// ---------------------------------------------------------------------------
// U split: U fp32 [M][256] -> Uh/Ul bf16 same layout
// ---------------------------------------------------------------------------
__global__ void usplit_kernel(const float* __restrict__ U,
                              ushort* __restrict__ uh, ushort* __restrict__ ul)
{
    int idx = blockIdx.x * 256 + threadIdx.x;   // cM*cD threads
    float x = U[idx];
    ushort h = f2bf(x);
    uh[idx] = h;
    ul[idx] = f2bf(x - bf2f(h));
}

// ---------------------------------------------------------------------------
// r[b][j] = tanh( concat([h,us,ue])[b] . WDw[:,j] + WDb[j] )
// ---------------------------------------------------------------------------
__global__ void r_kernel(const float* __restrict__ h, const float* __restrict__ us,
                         const float* __restrict__ ue,
                         const float* __restrict__ WDw, const float* __restrict__ WDb,
                         float* __restrict__ r)
{
    int b = blockIdx.x;
    int j = threadIdx.x;  // 128 threads
    __shared__ float x[640];
    x[j]       = h[b * cH + j];
    x[128 + j] = us[b * cD + j];
    x[256 + j] = us[b * cD + 128 + j];
    x[384 + j] = ue[b * cD + j];
    x[512 + j] = ue[b * cD + 128 + j];
    __syncthreads();
    float s = WDb[j];
    for (int k = 0; k < 640; ++k) s = fmaf(x[k], WDw[(size_t)k * cH + j], s);
    r[b * cH + j] = tanhf(s);
}

// ---------------------------------------------------------------------------
// rterm[b][n] = r[b] . W1r[:,n] + W1b[n]    (W1r = rows 256..383 of W1w)
// ---------------------------------------------------------------------------
__global__ void rterm_kernel(const float* __restrict__ r, const float* __restrict__ W1r,
                             const float* __restrict__ W1b, float* __restrict__ rterm)
{
    int b = blockIdx.y;
    int n = blockIdx.x * 256 + threadIdx.x;  // grid (8,32)
    __shared__ float rs[128];
    if (threadIdx.x < 128) rs[threadIdx.x] = r[b * cH + threadIdx.x];
    __syncthreads();
    float s = W1b[n];
    for (int k = 0; k < 128; ++k) s = fmaf(rs[k], W1r[(size_t)k * cN + n], s);
    rterm[(size_t)b * cN + n] = s;
}

// ---------------------------------------------------------------------------
// score[m] = max_p( concat([m1,m2])[m] . W3w[:,p] + W3b[p] ) -> ent region
// ---------------------------------------------------------------------------
__global__ __launch_bounds__(256)
void score_kernel(const float* __restrict__ m1, const float* __restrict__ m2,
                  const float* __restrict__ W3w, const float* __restrict__ W3b,
                  float* __restrict__ ent)
{
    __shared__ float xs[16][257];
    __shared__ float wsh[256 * 16];
    int tid = threadIdx.x;
    int m0 = blockIdx.x * 16;
    #pragma unroll
    for (int q = 0; q < 16; ++q) wsh[tid + q * 256] = W3w[tid + q * 256];
    #pragma unroll
    for (int q = 0; q < 8; ++q) {
        int f = tid + q * 256;
        int rl = f >> 7, col = f & 127;
        xs[rl][col]       = m1[(size_t)(m0 + rl) * cH + col];
        xs[rl][128 + col] = m2[(size_t)(m0 + rl) * cH + col];
    }
    __syncthreads();
    int rl = tid >> 4, p = tid & 15;
    float s = W3b[p];
    for (int k = 0; k < 256; ++k) s = fmaf(xs[rl][k], wsh[k * 16 + p], s);
    #pragma unroll
    for (int off = 8; off; off >>= 1) s = fmaxf(s, __shfl_xor(s, off));
    if (p == 0) ent[m0 + rl] = s;
}

// ---------------------------------------------------------------------------
// argmax over T per batch (first-occurrence ties), write float index,
// gather U row into us/ue
// ---------------------------------------------------------------------------
__global__ void argmax_kernel(const float* __restrict__ sc, const float* __restrict__ U,
                              float* __restrict__ uvec, float* __restrict__ outidx)
{
    int b = blockIdx.x;
    int tid = threadIdx.x;  // 256
    float bv = -3.4e38f;
    int bi = 0x7fffffff;
    for (int t = tid; t < cT; t += 256) {
        float v = sc[b * cT + t];
        if (v > bv || (v == bv && t < bi)) { bv = v; bi = t; }
    }
    __shared__ float vs[256];
    __shared__ int   is[256];
    vs[tid] = bv; is[tid] = bi;
    __syncthreads();
    for (int s = 128; s > 0; s >>= 1) {
        if (tid < s) {
            if (vs[tid + s] > vs[tid] ||
                (vs[tid + s] == vs[tid] && is[tid + s] < is[tid])) {
                vs[tid] = vs[tid + s];
                is[tid] = is[tid + s];
            }
        }
        __syncthreads();
    }
    int best = is[0];
    if (tid == 0) outidx[b] = (float)best;
    uvec[b * cD + tid % cD] = U[((size_t)b * cT + best) * cD + (tid % cD)];
}

// ---------------------------------------------------------------------------
// LSTM cell
// ---------------------------------------------------------------------------
__global__ void lstm_kernel(const float* __restrict__ us, const float* __restrict__ ue,
                            float* __restrict__ h, float* __restrict__ c,
                            const float* __restrict__ wih, const float* __restrict__ whh,
                            const float* __restrict__ bih, const float* __restrict__ bhh)
{
    int b = blockIdx.x;
    int j = threadIdx.x;  // 128
    __shared__ float x[512];
    __shared__ float hh[128];
    x[j]       = us[b * cD + j];
    x[128 + j] = us[b * cD + 128 + j];
    x[256 + j] = ue[b * cD + j];
    x[384 + j] = ue[b * cD + 128 + j];
    hh[j] = h[b * cH + j];
    __syncthreads();
    float g4[4];
    #pragma unroll
    for (int gi = 0; gi < 4; ++gi) {
        int row = gi * 128 + j;
        float s = bih[row] + bhh[row];
        const float* wr = wih + (size_t)row * 512;
        for (int k = 0; k < 512; ++k) s = fmaf(x[k], wr[k], s);
        const float* wr2 = whh + (size_t)row * 128;
        for (int k = 0; k < 128; ++k) s = fmaf(hh[k], wr2[k], s);
        g4[gi] = s;
    }
    float i_ = 1.f / (1.f + expf(-g4[0]));
    float f_ = 1.f / (1.f + expf(-g4[1]));
    float g_ = tanhf(g4[2]);
    float o_ = 1.f / (1.f + expf(-g4[3]));
    float c2 = f_ * c[b * cH + j] + i_ * g_;
    float h2 = o_ * tanhf(c2);
    c[b * cH + j] = c2;
    h[b * cH + j] = h2;
}

__global__ void init_kernel(const float* __restrict__ U, float* __restrict__ us,
                            float* __restrict__ ue, float* __restrict__ h,
                            float* __restrict__ c)
{
    int i = blockIdx.x * 256 + threadIdx.x;  // 8192 threads
    if (i < cB * cD) {
        int b = i >> 8, d = i & 255;
        us[i] = U[((size_t)b * cT + 0) * cD + d];
        ue[i] = U[((size_t)b * cT + 1) * cD + d];
    }
    if (i < cB * cH) { h[i] = 0.f; c[i] = 0.f; }
}

// ---------------------------------------------------------------------------
extern "C" void kernel_launch(void* const* d_in, const int* in_sizes, int n_in,
                              void* d_out, int out_size, void* d_ws, size_t ws_size,
                              hipStream_t stream)
{
    const float* U = (const float*)d_in[0];
    const float* WD_w[2] = {(const float*)d_in[1], (const float*)d_in[9]};
    const float* WD_b[2] = {(const float*)d_in[2], (const float*)d_in[10]};
    const float* W1_w[2] = {(const float*)d_in[3], (const float*)d_in[11]};
    const float* W1_b[2] = {(const float*)d_in[4], (const float*)d_in[12]};
    const float* W2_w[2] = {(const float*)d_in[5], (const float*)d_in[13]};
    const float* W2_b[2] = {(const float*)d_in[6], (const float*)d_in[14]};
    const float* W3_w[2] = {(const float*)d_in[7], (const float*)d_in[15]};
    const float* W3_b[2] = {(const float*)d_in[8], (const float*)d_in[16]};
    const float* wih = (const float*)d_in[17];
    const float* whh = (const float*)d_in[18];
    const float* bih = (const float*)d_in[19];
    const float* bhh = (const float*)d_in[20];

    float* ws = (float*)d_ws;
    float* m1 = ws;                               // 4M floats
    float* m2 = m1 + (size_t)cM * cH;             // 4M
    float* us = m2 + (size_t)cM * cH;
    float* ue = us + cB * cD;
    float* h  = ue + cB * cD;
    float* c  = h + cB * cH;
    float* r  = c + cB * cH;
    float* rterm = r + cB * cH;                   // 64K
    float* cur = rterm + (size_t)cB * cN;

    ushort* m1h = (ushort*)cur;                   cur += (size_t)cM * cH / 2;
    ushort* m1l = (ushort*)cur;                   cur += (size_t)cM * cH / 2;
    ushort* Uh  = (ushort*)cur;                   cur += (size_t)cM * cD / 2;
    ushort* Ul  = (ushort*)cur;                   cur += (size_t)cM * cD / 2;
    ushort* W1th[2], *W1tl[2], *W2th[2], *W2tl[2];
    for (int sd = 0; sd < 2; ++sd) {
        W1th[sd] = (ushort*)cur; cur += (size_t)cN * cD / 2;   // [2048][256]
        W1tl[sd] = (ushort*)cur; cur += (size_t)cN * cD / 2;
        W2th[sd] = (ushort*)cur; cur += (size_t)cN * cH / 2;   // [2048][128]
        W2tl[sd] = (ushort*)cur; cur += (size_t)cN * cH / 2;
    }
    float* A1[2];
    A1[0] = cur;
    A1[1] = A1[0] + (size_t)cM * cN;              // 64M floats each
    size_t need = (size_t)(A1[1] - ws) + (size_t)cM * cN;
    bool pre = ws_size >= need * sizeof(float);

    float* outf = (float*)d_out;

    init_kernel<<<32, 256, 0, stream>>>(U, us, ue, h, c);
    usplit_kernel<<<(cM * cD) / 256, 256, 0, stream>>>(U, Uh, Ul);
    for (int sd = 0; sd < 2; ++sd) {
        wsplit_kernel<<<(cD * cN) / 256, 256, 0, stream>>>(
            W1_w[sd], cD, cN, W1th[sd], W1tl[sd]);     // first 256 rows of W1
        wsplit_kernel<<<(cH * cN) / 256, 256, 0, stream>>>(
            W2_w[sd], cH, cN, W2th[sd], W2tl[sd]);
    }

    if (pre) {
        // A1 = U @ W1w[0:256,:] once per weight set (constant across iters)
        for (int sd = 0; sd < 2; ++sd)
            mfma_a1_ws<<<256, 256, 0, stream>>>(
                Uh, Ul, W1th[sd], W1tl[sd], A1[sd]);
    }

    const int gfall = (cN / 128) * (cM / 128);   // 4096 (fallback grid)
    for (int it = 0; it < 4; ++it) {
        for (int sd = 0; sd < 2; ++sd) {
            r_kernel<<<32, 128, 0, stream>>>(h, us, ue, WD_w[sd], WD_b[sd], r);
            rterm_kernel<<<dim3(8, 32), 256, 0, stream>>>(
                r, W1_w[sd] + (size_t)256 * cN, W1_b[sd], rterm);
            if (pre) {
                m1_from_a1_kernel<<<16384, 256, 0, stream>>>(
                    A1[sd], rterm, m1, m1h, m1l);
            } else {
                mfma_pool_swp<256, true><<<gfall, 256, 0, stream>>>(
                    W1th[sd], W1tl[sd], Uh, Ul, rterm, cN, m1, m1h, m1l);
            }
            // m2 = pool(m1 @ W2 + b2) -> fp32 (weight-stationary, 1 blk/CU)
            mfma_pool_ws<<<256, 256, 0, stream>>>(
                W2th[sd], W2tl[sd], m1h, m1l, W2_b[sd], m2);
            float* ent = outf + 64 + (size_t)(it * 2 + sd) * cB * cT;
            score_kernel<<<2048, 256, 0, stream>>>(m1, m2, W3_w[sd], W3_b[sd], ent);
            argmax_kernel<<<32, 256, 0, stream>>>(ent, U, sd ? ue : us,
                                                  outf + (sd ? 32 : 0));
        }
        lstm_kernel<<<32, 128, 0, stream>>>(us, ue, h, c, wih, whh, bih, bhh);
    }
}

// Round 12
// 2863.806 us; speedup vs baseline: 1.2293x; 1.1166x over previous
//
#include <hip/hip_runtime.h>
#include <math.h>

// Problem constants
static constexpr int cB = 32;
static constexpr int cT = 1024;
static constexpr int cH = 128;
static constexpr int cD = 256;   // 2H
static constexpr int cN = 2048;  // H*POOL
static constexpr int cM = cB * cT; // 32768

typedef __attribute__((ext_vector_type(8))) short short8;
typedef __attribute__((ext_vector_type(4))) float f32x4;

__device__ __forceinline__ ushort f2bf(float x) {
    union { float f; unsigned u; } v; v.f = x;
    unsigned r = v.u + 0x7FFF + ((v.u >> 16) & 1);   // RNE to bf16
    return (ushort)(r >> 16);
}
__device__ __forceinline__ float bf2f(ushort h) {
    union { float f; unsigned u; } v; v.u = ((unsigned)h) << 16;
    return v.f;
}

// async global->LDS, 16B per lane, wave-uniform LDS base + lane*16
__device__ __forceinline__ void gload_lds16(const ushort* g, ushort* l) {
    __builtin_amdgcn_global_load_lds(
        (const __attribute__((address_space(1))) unsigned int*)(const void*)g,
        (__attribute__((address_space(3))) unsigned int*)(void*)l,
        16, 0, 0);
}

// ---------------------------------------------------------------------------
// SWAPPED pooled GEMM (round-9 verified, best measured config):
//   out[m][o] = max_{p<16}( sum_k X[m][k]*Wt[16o+p][k] + initv[ib][16o+p] )
// C^T via mfma(Wfrag, Xfrag): pool = 3 in-lane fmax + shfl_xor(16,32).
// Per 128-k half: stage Wt (128x128 hi/lo = 64KB) via gload_lds + hoist all
// X frags (32 loads) -> ONE barrier -> 4 k-steps of pure ds_read+MFMA.
// 3-term split ah*bh+ah*bl+al*bh, fp32 acc. Block 256thr = 4 waves (2x2).
// 1-D grid 4096, bijective XCD-chunked remap. LDS swizzle: slot s of row r
// holds chunk s^(r&7) (source-side); read applies same XOR.
// ---------------------------------------------------------------------------
template<int K, bool WRITE_HL>
__global__ __launch_bounds__(256, 2)
void mfma_pool_swp(const ushort* __restrict__ Wth, const ushort* __restrict__ Wtl,
                   const ushort* __restrict__ Xh, const ushort* __restrict__ Xl,
                   const float* __restrict__ initv, int init_bstride,
                   float* __restrict__ out, ushort* __restrict__ outh,
                   ushort* __restrict__ outl)
{
    constexpr int KH = K / 128;
    __shared__ __attribute__((aligned(16))) ushort sWh[128 * 128];
    __shared__ __attribute__((aligned(16))) ushort sWl[128 * 128];

    const int tid  = threadIdx.x;
    const int wave = tid >> 6;
    const int lane = tid & 63;
    const int l15  = lane & 15;
    const int lg   = lane >> 4;
    const int wr   = wave >> 1;         // n-half
    const int wc   = wave & 1;          // m-half

    const int wg  = blockIdx.x;
    const int lin = (wg & 7) * 512 + (wg >> 3);
    const int bx  = lin & 15;
    const int by  = lin >> 4;
    const int n0  = bx * 128;
    const int m0  = by * 128;
    const size_t ibase = (size_t)(m0 >> 10) * init_bstride;

    float ivv[4][4];
    #pragma unroll
    for (int rf = 0; rf < 4; ++rf)
        #pragma unroll
        for (int r = 0; r < 4; ++r)
            ivv[rf][r] = initv[ibase + n0 + wr * 64 + rf * 16 + lg * 4 + r];

    f32x4 acc[4][4];
    #pragma unroll
    for (int rf = 0; rf < 4; ++rf)
        #pragma unroll
        for (int cf = 0; cf < 4; ++cf)
            acc[rf][cf] = (f32x4){0.f, 0.f, 0.f, 0.f};

    const int st_row_lo = lane >> 4;
    const int st_slot   = lane & 15;

    #pragma unroll
    for (int kh = 0; kh < KH; ++kh) {
        const int kb = kh * 128;
        if (kh > 0) __syncthreads();

        #pragma unroll
        for (int j = 0; j < 8; ++j) {
            int i   = wave * 8 + j;
            int row = i * 4 + st_row_lo;
            int ck  = st_slot ^ (row & 7);
            size_t goff = (size_t)(n0 + row) * K + kb + ck * 8;
            gload_lds16(Wth + goff, sWh + i * 512);
            gload_lds16(Wtl + goff, sWl + i * 512);
        }
        short8 xh_[16], xl_[16];
        #pragma unroll
        for (int cf = 0; cf < 4; ++cf)
            #pragma unroll
            for (int ks = 0; ks < 4; ++ks) {
                size_t off = (size_t)(m0 + wc * 64 + cf * 16 + l15) * K
                           + kb + ks * 32 + lg * 8;
                xh_[cf * 4 + ks] = *(const short8*)(Xh + off);
                xl_[cf * 4 + ks] = *(const short8*)(Xl + off);
            }
        __syncthreads();

        #pragma unroll
        for (int ks = 0; ks < 4; ++ks) {
            short8 w_h[4], w_l[4];
            #pragma unroll
            for (int rf = 0; rf < 4; ++rf) {
                int row  = wr * 64 + rf * 16 + l15;
                int ck2  = ks * 4 + lg;
                int adr  = row * 128 + ((ck2 ^ (row & 7)) * 8);
                w_h[rf] = *(const short8*)(sWh + adr);
                w_l[rf] = *(const short8*)(sWl + adr);
            }
            #pragma unroll
            for (int rf = 0; rf < 4; ++rf)
                #pragma unroll
                for (int cf = 0; cf < 4; ++cf) {
                    acc[rf][cf] = __builtin_amdgcn_mfma_f32_16x16x32_bf16(
                        w_h[rf], xh_[cf * 4 + ks], acc[rf][cf], 0, 0, 0);
                    acc[rf][cf] = __builtin_amdgcn_mfma_f32_16x16x32_bf16(
                        w_l[rf], xh_[cf * 4 + ks], acc[rf][cf], 0, 0, 0);
                    acc[rf][cf] = __builtin_amdgcn_mfma_f32_16x16x32_bf16(
                        w_h[rf], xl_[cf * 4 + ks], acc[rf][cf], 0, 0, 0);
                }
        }
    }

    const int NP = 128;
    #pragma unroll
    for (int rf = 0; rf < 4; ++rf) {
        const int o2 = (n0 >> 4) + wr * 4 + rf;
        #pragma unroll
        for (int cf = 0; cf < 4; ++cf) {
            float v0 = acc[rf][cf][0] + ivv[rf][0];
            float v1 = acc[rf][cf][1] + ivv[rf][1];
            float v2 = acc[rf][cf][2] + ivv[rf][2];
            float v3 = acc[rf][cf][3] + ivv[rf][3];
            float mx = fmaxf(fmaxf(v0, v1), fmaxf(v2, v3));
            mx = fmaxf(mx, __shfl_xor(mx, 16));
            mx = fmaxf(mx, __shfl_xor(mx, 32));
            if (lane < 16) {
                int m = m0 + wc * 64 + cf * 16 + lane;
                size_t o = (size_t)m * NP + o2;
                out[o] = mx;
                if (WRITE_HL) {
                    ushort hb = f2bf(mx);
                    outh[o] = hb;
                    outl[o] = f2bf(mx - bf2f(hb));
                }
            }
        }
    }
}

// ---------------------------------------------------------------------------
// A1 GEMM (no pool), K=256: out[m][n] = sum_k U[m][k]*W1t[n][k], fp32 out.
// Round-9 structure (LDS-staged W, hoisted X, (256,2)); unswapped orientation
// for coalesced 268MB writes. Runs once per weight-set when A1 fits in ws.
// ---------------------------------------------------------------------------
__global__ __launch_bounds__(256, 2)
void mfma_gemm_a1(const ushort* __restrict__ Uh, const ushort* __restrict__ Ul,
                  const ushort* __restrict__ Bth, const ushort* __restrict__ Btl,
                  float* __restrict__ out)
{
    constexpr int K = 256;
    __shared__ __attribute__((aligned(16))) ushort sBh[128 * 128];
    __shared__ __attribute__((aligned(16))) ushort sBl[128 * 128];

    const int tid  = threadIdx.x;
    const int wave = tid >> 6;
    const int lane = tid & 63;
    const int l15  = lane & 15;
    const int lg   = lane >> 4;
    const int wr   = wave >> 1;         // m-half
    const int wc   = wave & 1;          // n-half

    const int wg  = blockIdx.x;
    const int lin = (wg & 7) * 512 + (wg >> 3);
    const int bx  = lin & 15;
    const int by  = lin >> 4;
    const int n0  = bx * 128;
    const int m0  = by * 128;

    f32x4 acc[4][4];    // [mf][nf]
    #pragma unroll
    for (int mf = 0; mf < 4; ++mf)
        #pragma unroll
        for (int nf = 0; nf < 4; ++nf)
            acc[mf][nf] = (f32x4){0.f, 0.f, 0.f, 0.f};

    const int st_row_lo = lane >> 4;
    const int st_slot   = lane & 15;

    #pragma unroll
    for (int kh = 0; kh < 2; ++kh) {
        const int kb = kh * 128;
        if (kh > 0) __syncthreads();

        #pragma unroll
        for (int j = 0; j < 8; ++j) {
            int i   = wave * 8 + j;
            int row = i * 4 + st_row_lo;
            int ck  = st_slot ^ (row & 7);
            size_t goff = (size_t)(n0 + row) * K + kb + ck * 8;
            gload_lds16(Bth + goff, sBh + i * 512);
            gload_lds16(Btl + goff, sBl + i * 512);
        }
        short8 ph[16], pl[16];
        #pragma unroll
        for (int mf = 0; mf < 4; ++mf)
            #pragma unroll
            for (int ks = 0; ks < 4; ++ks) {
                size_t off = (size_t)(m0 + wr * 64 + mf * 16 + l15) * K
                           + kb + ks * 32 + lg * 8;
                ph[mf * 4 + ks] = *(const short8*)(Uh + off);
                pl[mf * 4 + ks] = *(const short8*)(Ul + off);
            }
        __syncthreads();

        #pragma unroll
        for (int ks = 0; ks < 4; ++ks) {
            short8 b_h[4], b_l[4];
            #pragma unroll
            for (int nf = 0; nf < 4; ++nf) {
                int row  = wc * 64 + nf * 16 + l15;
                int ck2  = ks * 4 + lg;
                int adr  = row * 128 + ((ck2 ^ (row & 7)) * 8);
                b_h[nf] = *(const short8*)(sBh + adr);
                b_l[nf] = *(const short8*)(sBl + adr);
            }
            #pragma unroll
            for (int mf = 0; mf < 4; ++mf)
                #pragma unroll
                for (int nf = 0; nf < 4; ++nf) {
                    acc[mf][nf] = __builtin_amdgcn_mfma_f32_16x16x32_bf16(
                        ph[mf * 4 + ks], b_h[nf], acc[mf][nf], 0, 0, 0);
                    acc[mf][nf] = __builtin_amdgcn_mfma_f32_16x16x32_bf16(
                        ph[mf * 4 + ks], b_l[nf], acc[mf][nf], 0, 0, 0);
                    acc[mf][nf] = __builtin_amdgcn_mfma_f32_16x16x32_bf16(
                        pl[mf * 4 + ks], b_h[nf], acc[mf][nf], 0, 0, 0);
                }
        }
    }

    #pragma unroll
    for (int mf = 0; mf < 4; ++mf)
        #pragma unroll
        for (int nf = 0; nf < 4; ++nf) {
            int col = n0 + wc * 64 + nf * 16 + l15;
            #pragma unroll
            for (int r = 0; r < 4; ++r) {
                int row = m0 + wr * 64 + mf * 16 + lg * 4 + r;
                out[(size_t)row * cN + col] = acc[mf][nf][r];
            }
        }
}

// ---------------------------------------------------------------------------
// m1[m][o] = max_p( A1[m][o*16+p] + rterm[b][o*16+p] ), also emits bf16 hi/lo
// ---------------------------------------------------------------------------
__global__ void m1_from_a1_kernel(const float* __restrict__ A1,
                                  const float* __restrict__ rterm,
                                  float* __restrict__ m1,
                                  ushort* __restrict__ m1h,
                                  ushort* __restrict__ m1l)
{
    int idx = blockIdx.x * 256 + threadIdx.x;   // [0, 32768*128)
    int m = idx >> 7;
    int o = idx & 127;
    int b = m >> 10;
    const float4* a  = (const float4*)(A1 + (size_t)m * cN + o * 16);
    const float4* rt = (const float4*)(rterm + (size_t)b * cN + o * 16);
    float mx = -3.4e38f;
    #pragma unroll
    for (int q = 0; q < 4; ++q) {
        float4 av = a[q];
        float4 rv = rt[q];
        mx = fmaxf(mx, fmaxf(fmaxf(av.x + rv.x, av.y + rv.y),
                             fmaxf(av.z + rv.z, av.w + rv.w)));
    }
    m1[idx] = mx;
    ushort hb = f2bf(mx);
    m1h[idx] = hb;
    m1l[idx] = f2bf(mx - bf2f(hb));
}

// ---------------------------------------------------------------------------
// Weight transpose + bf16 split: W[K x N] row-major -> Wt hi/lo [N][K]
// ---------------------------------------------------------------------------
__global__ void wsplit_kernel(const float* __restrict__ W, int K, int N,
                              ushort* __restrict__ th, ushort* __restrict__ tl)
{
    int idx = blockIdx.x * 256 + threadIdx.x;
    if (idx >= K * N) return;
    int k = idx / N, n = idx - k * N;      // coalesced read
    float x = W[idx];
    ushort h = f2bf(x);
    th[(size_t)n * K + k] = h;
    tl[(size_t)n * K + k] = f2bf(x - bf2f(h));
}

// ---------------------------------------------------------------------------
// U split: U fp32 [M][256] -> Uh/Ul bf16 same layout
// ---------------------------------------------------------------------------
__global__ void usplit_kernel(const float* __restrict__ U,
                              ushort* __restrict__ uh, ushort* __restrict__ ul)
{
    int idx = blockIdx.x * 256 + threadIdx.x;   // cM*cD threads
    float x = U[idx];
    ushort h = f2bf(x);
    uh[idx] = h;
    ul[idx] = f2bf(x - bf2f(h));
}

// ---------------------------------------------------------------------------
// r[b][j] = tanh( concat([h,us,ue])[b] . WDw[:,j] + WDb[j] )
// ---------------------------------------------------------------------------
__global__ void r_kernel(const float* __restrict__ h, const float* __restrict__ us,
                         const float* __restrict__ ue,
                         const float* __restrict__ WDw, const float* __restrict__ WDb,
                         float* __restrict__ r)
{
    int b = blockIdx.x;
    int j = threadIdx.x;  // 128 threads
    __shared__ float x[640];
    x[j]       = h[b * cH + j];
    x[128 + j] = us[b * cD + j];
    x[256 + j] = us[b * cD + 128 + j];
    x[384 + j] = ue[b * cD + j];
    x[512 + j] = ue[b * cD + 128 + j];
    __syncthreads();
    float s = WDb[j];
    for (int k = 0; k < 640; ++k) s = fmaf(x[k], WDw[(size_t)k * cH + j], s);
    r[b * cH + j] = tanhf(s);
}

// ---------------------------------------------------------------------------
// rterm[b][n] = r[b] . W1r[:,n] + W1b[n]    (W1r = rows 256..383 of W1w)
// ---------------------------------------------------------------------------
__global__ void rterm_kernel(const float* __restrict__ r, const float* __restrict__ W1r,
                             const float* __restrict__ W1b, float* __restrict__ rterm)
{
    int b = blockIdx.y;
    int n = blockIdx.x * 256 + threadIdx.x;  // grid (8,32)
    __shared__ float rs[128];
    if (threadIdx.x < 128) rs[threadIdx.x] = r[b * cH + threadIdx.x];
    __syncthreads();
    float s = W1b[n];
    for (int k = 0; k < 128; ++k) s = fmaf(rs[k], W1r[(size_t)k * cN + n], s);
    rterm[(size_t)b * cN + n] = s;
}

// ---------------------------------------------------------------------------
// score[m] = max_p( concat([m1,m2])[m] . W3w[:,p] + W3b[p] ) -> ent region
// ---------------------------------------------------------------------------
__global__ __launch_bounds__(256)
void score_kernel(const float* __restrict__ m1, const float* __restrict__ m2,
                  const float* __restrict__ W3w, const float* __restrict__ W3b,
                  float* __restrict__ ent)
{
    __shared__ float xs[16][257];
    __shared__ float wsh[256 * 16];
    int tid = threadIdx.x;
    int m0 = blockIdx.x * 16;
    #pragma unroll
    for (int q = 0; q < 16; ++q) wsh[tid + q * 256] = W3w[tid + q * 256];
    #pragma unroll
    for (int q = 0; q < 8; ++q) {
        int f = tid + q * 256;
        int rl = f >> 7, col = f & 127;
        xs[rl][col]       = m1[(size_t)(m0 + rl) * cH + col];
        xs[rl][128 + col] = m2[(size_t)(m0 + rl) * cH + col];
    }
    __syncthreads();
    int rl = tid >> 4, p = tid & 15;
    float s = W3b[p];
    for (int k = 0; k < 256; ++k) s = fmaf(xs[rl][k], wsh[k * 16 + p], s);
    #pragma unroll
    for (int off = 8; off; off >>= 1) s = fmaxf(s, __shfl_xor(s, off));
    if (p == 0) ent[m0 + rl] = s;
}

// ---------------------------------------------------------------------------
// argmax over T per batch (first-occurrence ties), write float index,
// gather U row into us/ue
// ---------------------------------------------------------------------------
__global__ void argmax_kernel(const float* __restrict__ sc, const float* __restrict__ U,
                              float* __restrict__ uvec, float* __restrict__ outidx)
{
    int b = blockIdx.x;
    int tid = threadIdx.x;  // 256
    float bv = -3.4e38f;
    int bi = 0x7fffffff;
    for (int t = tid; t < cT; t += 256) {
        float v = sc[b * cT + t];
        if (v > bv || (v == bv && t < bi)) { bv = v; bi = t; }
    }
    __shared__ float vs[256];
    __shared__ int   is[256];
    vs[tid] = bv; is[tid] = bi;
    __syncthreads();
    for (int s = 128; s > 0; s >>= 1) {
        if (tid < s) {
            if (vs[tid + s] > vs[tid] ||
                (vs[tid + s] == vs[tid] && is[tid + s] < is[tid])) {
                vs[tid] = vs[tid + s];
                is[tid] = is[tid + s];
            }
        }
        __syncthreads();
    }
    int best = is[0];
    if (tid == 0) outidx[b] = (float)best;
    uvec[b * cD + tid % cD] = U[((size_t)b * cT + best) * cD + (tid % cD)];
}

// ---------------------------------------------------------------------------
// LSTM cell
// ---------------------------------------------------------------------------
__global__ void lstm_kernel(const float* __restrict__ us, const float* __restrict__ ue,
                            float* __restrict__ h, float* __restrict__ c,
                            const float* __restrict__ wih, const float* __restrict__ whh,
                            const float* __restrict__ bih, const float* __restrict__ bhh)
{
    int b = blockIdx.x;
    int j = threadIdx.x;  // 128
    __shared__ float x[512];
    __shared__ float hh[128];
    x[j]       = us[b * cD + j];
    x[128 + j] = us[b * cD + 128 + j];
    x[256 + j] = ue[b * cD + j];
    x[384 + j] = ue[b * cD + 128 + j];
    hh[j] = h[b * cH + j];
    __syncthreads();
    float g4[4];
    #pragma unroll
    for (int gi = 0; gi < 4; ++gi) {
        int row = gi * 128 + j;
        float s = bih[row] + bhh[row];
        const float* wr = wih + (size_t)row * 512;
        for (int k = 0; k < 512; ++k) s = fmaf(x[k], wr[k], s);
        const float* wr2 = whh + (size_t)row * 128;
        for (int k = 0; k < 128; ++k) s = fmaf(hh[k], wr2[k], s);
        g4[gi] = s;
    }
    float i_ = 1.f / (1.f + expf(-g4[0]));
    float f_ = 1.f / (1.f + expf(-g4[1]));
    float g_ = tanhf(g4[2]);
    float o_ = 1.f / (1.f + expf(-g4[3]));
    float c2 = f_ * c[b * cH + j] + i_ * g_;
    float h2 = o_ * tanhf(c2);
    c[b * cH + j] = c2;
    h[b * cH + j] = h2;
}

__global__ void init_kernel(const float* __restrict__ U, float* __restrict__ us,
                            float* __restrict__ ue, float* __restrict__ h,
                            float* __restrict__ c)
{
    int i = blockIdx.x * 256 + threadIdx.x;  // 8192 threads
    if (i < cB * cD) {
        int b = i >> 8, d = i & 255;
        us[i] = U[((size_t)b * cT + 0) * cD + d];
        ue[i] = U[((size_t)b * cT + 1) * cD + d];
    }
    if (i < cB * cH) { h[i] = 0.f; c[i] = 0.f; }
}

// ---------------------------------------------------------------------------
extern "C" void kernel_launch(void* const* d_in, const int* in_sizes, int n_in,
                              void* d_out, int out_size, void* d_ws, size_t ws_size,
                              hipStream_t stream)
{
    const float* U = (const float*)d_in[0];
    const float* WD_w[2] = {(const float*)d_in[1], (const float*)d_in[9]};
    const float* WD_b[2] = {(const float*)d_in[2], (const float*)d_in[10]};
    const float* W1_w[2] = {(const float*)d_in[3], (const float*)d_in[11]};
    const float* W1_b[2] = {(const float*)d_in[4], (const float*)d_in[12]};
    const float* W2_w[2] = {(const float*)d_in[5], (const float*)d_in[13]};
    const float* W2_b[2] = {(const float*)d_in[6], (const float*)d_in[14]};
    const float* W3_w[2] = {(const float*)d_in[7], (const float*)d_in[15]};
    const float* W3_b[2] = {(const float*)d_in[8], (const float*)d_in[16]};
    const float* wih = (const float*)d_in[17];
    const float* whh = (const float*)d_in[18];
    const float* bih = (const float*)d_in[19];
    const float* bhh = (const float*)d_in[20];

    float* ws = (float*)d_ws;
    float* m1 = ws;                               // 4M floats
    float* m2 = m1 + (size_t)cM * cH;             // 4M
    float* us = m2 + (size_t)cM * cH;
    float* ue = us + cB * cD;
    float* h  = ue + cB * cD;
    float* c  = h + cB * cH;
    float* r  = c + cB * cH;
    float* rterm = r + cB * cH;                   // 64K
    float* cur = rterm + (size_t)cB * cN;

    ushort* m1h = (ushort*)cur;                   cur += (size_t)cM * cH / 2;
    ushort* m1l = (ushort*)cur;                   cur += (size_t)cM * cH / 2;
    ushort* Uh  = (ushort*)cur;                   cur += (size_t)cM * cD / 2;
    ushort* Ul  = (ushort*)cur;                   cur += (size_t)cM * cD / 2;
    ushort* W1th[2], *W1tl[2], *W2th[2], *W2tl[2];
    for (int sd = 0; sd < 2; ++sd) {
        W1th[sd] = (ushort*)cur; cur += (size_t)cN * cD / 2;   // [2048][256]
        W1tl[sd] = (ushort*)cur; cur += (size_t)cN * cD / 2;
        W2th[sd] = (ushort*)cur; cur += (size_t)cN * cH / 2;   // [2048][128]
        W2tl[sd] = (ushort*)cur; cur += (size_t)cN * cH / 2;
    }
    float* A1[2];
    A1[0] = cur;
    A1[1] = A1[0] + (size_t)cM * cN;              // 67.1M floats (268MB) each

    // Tiered precompute: how many A1 buffers fit in ws?
    size_t baseFloats = (size_t)(A1[0] - ws);
    int preN = 0;
    if (ws_size >= (baseFloats + 2 * (size_t)cM * cN) * sizeof(float)) preN = 2;
    else if (ws_size >= (baseFloats + (size_t)cM * cN) * sizeof(float)) preN = 1;

    float* outf = (float*)d_out;

    init_kernel<<<32, 256, 0, stream>>>(U, us, ue, h, c);
    usplit_kernel<<<(cM * cD) / 256, 256, 0, stream>>>(U, Uh, Ul);
    for (int sd = 0; sd < 2; ++sd) {
        wsplit_kernel<<<(cD * cN) / 256, 256, 0, stream>>>(
            W1_w[sd], cD, cN, W1th[sd], W1tl[sd]);     // first 256 rows of W1
        wsplit_kernel<<<(cH * cN) / 256, 256, 0, stream>>>(
            W2_w[sd], cH, cN, W2th[sd], W2tl[sd]);
    }

    const int ggrid = (cN / 128) * (cM / 128);   // 4096, 1-D (XCD swizzle inside)
    for (int sd = 0; sd < preN; ++sd)
        mfma_gemm_a1<<<ggrid, 256, 0, stream>>>(
            Uh, Ul, W1th[sd], W1tl[sd], A1[sd]);

    for (int it = 0; it < 4; ++it) {
        for (int sd = 0; sd < 2; ++sd) {
            r_kernel<<<32, 128, 0, stream>>>(h, us, ue, WD_w[sd], WD_b[sd], r);
            rterm_kernel<<<dim3(8, 32), 256, 0, stream>>>(
                r, W1_w[sd] + (size_t)256 * cN, W1_b[sd], rterm);
            if (sd < preN) {
                m1_from_a1_kernel<<<16384, 256, 0, stream>>>(
                    A1[sd], rterm, m1, m1h, m1l);
            } else {
                mfma_pool_swp<256, true><<<ggrid, 256, 0, stream>>>(
                    W1th[sd], W1tl[sd], Uh, Ul, rterm, cN, m1, m1h, m1l);
            }
            // m2 = pool(m1 @ W2 + b2) -> fp32 (round-9 verified kernel)
            mfma_pool_swp<128, false><<<ggrid, 256, 0, stream>>>(
                W2th[sd], W2tl[sd], m1h, m1l, W2_b[sd], 0, m2, nullptr, nullptr);
            float* ent = outf + 64 + (size_t)(it * 2 + sd) * cB * cT;
            score_kernel<<<2048, 256, 0, stream>>>(m1, m2, W3_w[sd], W3_b[sd], ent);
            argmax_kernel<<<32, 256, 0, stream>>>(ent, U, sd ? ue : us,
                                                  outf + (sd ? 32 : 0));
        }
        lstm_kernel<<<32, 128, 0, stream>>>(us, ue, h, c, wih, whh, bih, bhh);
    }
}

// Round 13
// 2802.301 us; speedup vs baseline: 1.2563x; 1.0219x over previous
//
#include <hip/hip_runtime.h>
#include <math.h>

// Problem constants
static constexpr int cB = 32;
static constexpr int cT = 1024;
static constexpr int cH = 128;
static constexpr int cD = 256;   // 2H
static constexpr int cN = 2048;  // H*POOL
static constexpr int cM = cB * cT; // 32768

typedef __attribute__((ext_vector_type(8))) short short8;
typedef __attribute__((ext_vector_type(4))) float f32x4;

__device__ __forceinline__ ushort f2bf(float x) {
    union { float f; unsigned u; } v; v.f = x;
    unsigned r = v.u + 0x7FFF + ((v.u >> 16) & 1);   // RNE to bf16
    return (ushort)(r >> 16);
}
__device__ __forceinline__ float bf2f(ushort h) {
    union { float f; unsigned u; } v; v.u = ((unsigned)h) << 16;
    return v.f;
}

// async global->LDS, 16B per lane, wave-uniform LDS base + lane*16
__device__ __forceinline__ void gload_lds16(const ushort* g, ushort* l) {
    __builtin_amdgcn_global_load_lds(
        (const __attribute__((address_space(1))) unsigned int*)(const void*)g,
        (__attribute__((address_space(3))) unsigned int*)(void*)l,
        16, 0, 0);
}

// ---------------------------------------------------------------------------
// MULTI-SUBTILE pooled m2 GEMM (K=128, S=4):
//   out[m][o] = max_{p<16}( sum_k X[m][k]*Wt[16o+p][k] + bias[16o+p] )
// Diagnosis (r6-r12): K=256 and K=128 both ran 197us -> time is per-block
// FIXED cost (stage+drain+barrier+epilogue), not K-loop work. Fix: stage the
// whole W panel (64KB hi/lo) ONCE, one barrier, then S=4 m-subtiles (512
// rows) completely barrier-free — LDS is read-only, X loads of subtile s+1
// overlap MFMAs of subtile s, fixed cost amortized 4x. Grid 1024, 2 blk/CU.
// Swapped orientation mfma(W,X): pool = 3 in-lane fmax + shfl_xor(16,32).
// 3-term split wh*xh+wl*xh+wh*xl, fp32 acc. Block 256thr = 4 waves (2x2).
// XCD-chunked bijective remap (per XCD: 8 by x 16 bx -> X 2MB + W 1MB in L2).
// LDS swizzle: slot s of row r holds chunk s^(r&7); read applies same XOR.
// ---------------------------------------------------------------------------
__global__ __launch_bounds__(256, 2)
void mfma_pool_m2(const ushort* __restrict__ Wth, const ushort* __restrict__ Wtl,
                  const ushort* __restrict__ Xh, const ushort* __restrict__ Xl,
                  const float* __restrict__ bias, float* __restrict__ out)
{
    constexpr int K = 128, S = 4;
    __shared__ __attribute__((aligned(16))) ushort sWh[128 * 128];  // 32KB
    __shared__ __attribute__((aligned(16))) ushort sWl[128 * 128];  // 32KB

    const int tid  = threadIdx.x;
    const int wave = tid >> 6;
    const int lane = tid & 63;
    const int l15  = lane & 15;
    const int lg   = lane >> 4;
    const int wr   = wave >> 1;         // n-half
    const int wc   = wave & 1;          // m-half

    const int wg  = blockIdx.x;                  // grid 1024
    const int lin = (wg & 7) * 128 + (wg >> 3);  // XCD-chunked, bijective
    const int bx  = lin & 15;                    // n block
    const int by  = lin >> 4;                    // m group (512 rows)
    const int n0  = bx * 128;

    // bias per (rf, reg r): n = n0 + wr*64 + rf*16 + lg*4 + r
    float ivv[4][4];
    #pragma unroll
    for (int rf = 0; rf < 4; ++rf)
        #pragma unroll
        for (int r = 0; r < 4; ++r)
            ivv[rf][r] = bias[n0 + wr * 64 + rf * 16 + lg * 4 + r];

    // ---- stage W panel once (per plane: 32 x 1KB instrs, 8 per wave) ------
    const int st_row_lo = lane >> 4;    // 0..3
    const int st_slot   = lane & 15;
    #pragma unroll
    for (int j = 0; j < 8; ++j) {
        int i   = wave * 8 + j;             // 0..31
        int row = i * 4 + st_row_lo;        // 0..127
        int ck  = st_slot ^ (row & 7);
        size_t goff = (size_t)(n0 + row) * K + ck * 8;
        gload_lds16(Wth + goff, sWh + i * 512);
        gload_lds16(Wtl + goff, sWl + i * 512);
    }
    __syncthreads();        // ONLY barrier: W valid, read-only afterwards

    const int NP = 128;
    #pragma unroll
    for (int s = 0; s < S; ++s) {
        const int m0 = by * 512 + s * 128;

        short8 xh_[16], xl_[16];    // [cf*4+ks]
        #pragma unroll
        for (int cf = 0; cf < 4; ++cf)
            #pragma unroll
            for (int ks = 0; ks < 4; ++ks) {
                size_t off = (size_t)(m0 + wc * 64 + cf * 16 + l15) * K
                           + ks * 32 + lg * 8;
                xh_[cf * 4 + ks] = *(const short8*)(Xh + off);
                xl_[cf * 4 + ks] = *(const short8*)(Xl + off);
            }

        f32x4 acc[4][4];    // [rf][cf]
        #pragma unroll
        for (int rf = 0; rf < 4; ++rf)
            #pragma unroll
            for (int cf = 0; cf < 4; ++cf)
                acc[rf][cf] = (f32x4){0.f, 0.f, 0.f, 0.f};

        #pragma unroll
        for (int ks = 0; ks < 4; ++ks) {
            short8 w_h[4], w_l[4];
            #pragma unroll
            for (int rf = 0; rf < 4; ++rf) {
                int row  = wr * 64 + rf * 16 + l15;
                int ck2  = ks * 4 + lg;
                int adr  = row * 128 + ((ck2 ^ (row & 7)) * 8);
                w_h[rf] = *(const short8*)(sWh + adr);
                w_l[rf] = *(const short8*)(sWl + adr);
            }
            #pragma unroll
            for (int rf = 0; rf < 4; ++rf)
                #pragma unroll
                for (int cf = 0; cf < 4; ++cf) {
                    acc[rf][cf] = __builtin_amdgcn_mfma_f32_16x16x32_bf16(
                        w_h[rf], xh_[cf * 4 + ks], acc[rf][cf], 0, 0, 0);
                    acc[rf][cf] = __builtin_amdgcn_mfma_f32_16x16x32_bf16(
                        w_l[rf], xh_[cf * 4 + ks], acc[rf][cf], 0, 0, 0);
                    acc[rf][cf] = __builtin_amdgcn_mfma_f32_16x16x32_bf16(
                        w_h[rf], xl_[cf * 4 + ks], acc[rf][cf], 0, 0, 0);
                }
        }

        // pool + write (no barrier needed — LDS untouched)
        #pragma unroll
        for (int rf = 0; rf < 4; ++rf) {
            const int o2 = (n0 >> 4) + wr * 4 + rf;
            #pragma unroll
            for (int cf = 0; cf < 4; ++cf) {
                float v0 = acc[rf][cf][0] + ivv[rf][0];
                float v1 = acc[rf][cf][1] + ivv[rf][1];
                float v2 = acc[rf][cf][2] + ivv[rf][2];
                float v3 = acc[rf][cf][3] + ivv[rf][3];
                float mx = fmaxf(fmaxf(v0, v1), fmaxf(v2, v3));
                mx = fmaxf(mx, __shfl_xor(mx, 16));
                mx = fmaxf(mx, __shfl_xor(mx, 32));
                if (lane < 16) {
                    int m = m0 + wc * 64 + cf * 16 + lane;
                    out[(size_t)m * NP + o2] = mx;
                }
            }
        }
    }
}

// ---------------------------------------------------------------------------
// SWAPPED pooled GEMM (round-9 verified) — fused m1 (K=256) path.
// ---------------------------------------------------------------------------
template<int K, bool WRITE_HL>
__global__ __launch_bounds__(256, 2)
void mfma_pool_swp(const ushort* __restrict__ Wth, const ushort* __restrict__ Wtl,
                   const ushort* __restrict__ Xh, const ushort* __restrict__ Xl,
                   const float* __restrict__ initv, int init_bstride,
                   float* __restrict__ out, ushort* __restrict__ outh,
                   ushort* __restrict__ outl)
{
    constexpr int KH = K / 128;
    __shared__ __attribute__((aligned(16))) ushort sWh[128 * 128];
    __shared__ __attribute__((aligned(16))) ushort sWl[128 * 128];

    const int tid  = threadIdx.x;
    const int wave = tid >> 6;
    const int lane = tid & 63;
    const int l15  = lane & 15;
    const int lg   = lane >> 4;
    const int wr   = wave >> 1;         // n-half
    const int wc   = wave & 1;          // m-half

    const int wg  = blockIdx.x;
    const int lin = (wg & 7) * 512 + (wg >> 3);
    const int bx  = lin & 15;
    const int by  = lin >> 4;
    const int n0  = bx * 128;
    const int m0  = by * 128;
    const size_t ibase = (size_t)(m0 >> 10) * init_bstride;

    float ivv[4][4];
    #pragma unroll
    for (int rf = 0; rf < 4; ++rf)
        #pragma unroll
        for (int r = 0; r < 4; ++r)
            ivv[rf][r] = initv[ibase + n0 + wr * 64 + rf * 16 + lg * 4 + r];

    f32x4 acc[4][4];
    #pragma unroll
    for (int rf = 0; rf < 4; ++rf)
        #pragma unroll
        for (int cf = 0; cf < 4; ++cf)
            acc[rf][cf] = (f32x4){0.f, 0.f, 0.f, 0.f};

    const int st_row_lo = lane >> 4;
    const int st_slot   = lane & 15;

    #pragma unroll
    for (int kh = 0; kh < KH; ++kh) {
        const int kb = kh * 128;
        if (kh > 0) __syncthreads();

        #pragma unroll
        for (int j = 0; j < 8; ++j) {
            int i   = wave * 8 + j;
            int row = i * 4 + st_row_lo;
            int ck  = st_slot ^ (row & 7);
            size_t goff = (size_t)(n0 + row) * K + kb + ck * 8;
            gload_lds16(Wth + goff, sWh + i * 512);
            gload_lds16(Wtl + goff, sWl + i * 512);
        }
        short8 xh_[16], xl_[16];
        #pragma unroll
        for (int cf = 0; cf < 4; ++cf)
            #pragma unroll
            for (int ks = 0; ks < 4; ++ks) {
                size_t off = (size_t)(m0 + wc * 64 + cf * 16 + l15) * K
                           + kb + ks * 32 + lg * 8;
                xh_[cf * 4 + ks] = *(const short8*)(Xh + off);
                xl_[cf * 4 + ks] = *(const short8*)(Xl + off);
            }
        __syncthreads();

        #pragma unroll
        for (int ks = 0; ks < 4; ++ks) {
            short8 w_h[4], w_l[4];
            #pragma unroll
            for (int rf = 0; rf < 4; ++rf) {
                int row  = wr * 64 + rf * 16 + l15;
                int ck2  = ks * 4 + lg;
                int adr  = row * 128 + ((ck2 ^ (row & 7)) * 8);
                w_h[rf] = *(const short8*)(sWh + adr);
                w_l[rf] = *(const short8*)(sWl + adr);
            }
            #pragma unroll
            for (int rf = 0; rf < 4; ++rf)
                #pragma unroll
                for (int cf = 0; cf < 4; ++cf) {
                    acc[rf][cf] = __builtin_amdgcn_mfma_f32_16x16x32_bf16(
                        w_h[rf], xh_[cf * 4 + ks], acc[rf][cf], 0, 0, 0);
                    acc[rf][cf] = __builtin_amdgcn_mfma_f32_16x16x32_bf16(
                        w_l[rf], xh_[cf * 4 + ks], acc[rf][cf], 0, 0, 0);
                    acc[rf][cf] = __builtin_amdgcn_mfma_f32_16x16x32_bf16(
                        w_h[rf], xl_[cf * 4 + ks], acc[rf][cf], 0, 0, 0);
                }
        }
    }

    const int NP = 128;
    #pragma unroll
    for (int rf = 0; rf < 4; ++rf) {
        const int o2 = (n0 >> 4) + wr * 4 + rf;
        #pragma unroll
        for (int cf = 0; cf < 4; ++cf) {
            float v0 = acc[rf][cf][0] + ivv[rf][0];
            float v1 = acc[rf][cf][1] + ivv[rf][1];
            float v2 = acc[rf][cf][2] + ivv[rf][2];
            float v3 = acc[rf][cf][3] + ivv[rf][3];
            float mx = fmaxf(fmaxf(v0, v1), fmaxf(v2, v3));
            mx = fmaxf(mx, __shfl_xor(mx, 16));
            mx = fmaxf(mx, __shfl_xor(mx, 32));
            if (lane < 16) {
                int m = m0 + wc * 64 + cf * 16 + lane;
                size_t o = (size_t)m * NP + o2;
                out[o] = mx;
                if (WRITE_HL) {
                    ushort hb = f2bf(mx);
                    outh[o] = hb;
                    outl[o] = f2bf(mx - bf2f(hb));
                }
            }
        }
    }
}

// ---------------------------------------------------------------------------
// Weight transpose + bf16 split: W[K x N] row-major -> Wt hi/lo [N][K]
// ---------------------------------------------------------------------------
__global__ void wsplit_kernel(const float* __restrict__ W, int K, int N,
                              ushort* __restrict__ th, ushort* __restrict__ tl)
{
    int idx = blockIdx.x * 256 + threadIdx.x;
    if (idx >= K * N) return;
    int k = idx / N, n = idx - k * N;      // coalesced read
    float x = W[idx];
    ushort h = f2bf(x);
    th[(size_t)n * K + k] = h;
    tl[(size_t)n * K + k] = f2bf(x - bf2f(h));
}

// ---------------------------------------------------------------------------
// U split: U fp32 [M][256] -> Uh/Ul bf16 same layout
// ---------------------------------------------------------------------------
__global__ void usplit_kernel(const float* __restrict__ U,
                              ushort* __restrict__ uh, ushort* __restrict__ ul)
{
    int idx = blockIdx.x * 256 + threadIdx.x;   // cM*cD threads
    float x = U[idx];
    ushort h = f2bf(x);
    uh[idx] = h;
    ul[idx] = f2bf(x - bf2f(h));
}

// ---------------------------------------------------------------------------
// r[b][j] = tanh( concat([h,us,ue])[b] . WDw[:,j] + WDb[j] )
// ---------------------------------------------------------------------------
__global__ void r_kernel(const float* __restrict__ h, const float* __restrict__ us,
                         const float* __restrict__ ue,
                         const float* __restrict__ WDw, const float* __restrict__ WDb,
                         float* __restrict__ r)
{
    int b = blockIdx.x;
    int j = threadIdx.x;  // 128 threads
    __shared__ float x[640];
    x[j]       = h[b * cH + j];
    x[128 + j] = us[b * cD + j];
    x[256 + j] = us[b * cD + 128 + j];
    x[384 + j] = ue[b * cD + j];
    x[512 + j] = ue[b * cD + 128 + j];
    __syncthreads();
    float s = WDb[j];
    for (int k = 0; k < 640; ++k) s = fmaf(x[k], WDw[(size_t)k * cH + j], s);
    r[b * cH + j] = tanhf(s);
}

// ---------------------------------------------------------------------------
// rterm[b][n] = r[b] . W1r[:,n] + W1b[n]    (W1r = rows 256..383 of W1w)
// ---------------------------------------------------------------------------
__global__ void rterm_kernel(const float* __restrict__ r, const float* __restrict__ W1r,
                             const float* __restrict__ W1b, float* __restrict__ rterm)
{
    int b = blockIdx.y;
    int n = blockIdx.x * 256 + threadIdx.x;  // grid (8,32)
    __shared__ float rs[128];
    if (threadIdx.x < 128) rs[threadIdx.x] = r[b * cH + threadIdx.x];
    __syncthreads();
    float s = W1b[n];
    for (int k = 0; k < 128; ++k) s = fmaf(rs[k], W1r[(size_t)k * cN + n], s);
    rterm[(size_t)b * cN + n] = s;
}

// ---------------------------------------------------------------------------
// score[m] = max_p( concat([m1,m2])[m] . W3w[:,p] + W3b[p] ) -> ent region
// ---------------------------------------------------------------------------
__global__ __launch_bounds__(256)
void score_kernel(const float* __restrict__ m1, const float* __restrict__ m2,
                  const float* __restrict__ W3w, const float* __restrict__ W3b,
                  float* __restrict__ ent)
{
    __shared__ float xs[16][257];
    __shared__ float wsh[256 * 16];
    int tid = threadIdx.x;
    int m0 = blockIdx.x * 16;
    #pragma unroll
    for (int q = 0; q < 16; ++q) wsh[tid + q * 256] = W3w[tid + q * 256];
    #pragma unroll
    for (int q = 0; q < 8; ++q) {
        int f = tid + q * 256;
        int rl = f >> 7, col = f & 127;
        xs[rl][col]       = m1[(size_t)(m0 + rl) * cH + col];
        xs[rl][128 + col] = m2[(size_t)(m0 + rl) * cH + col];
    }
    __syncthreads();
    int rl = tid >> 4, p = tid & 15;
    float s = W3b[p];
    for (int k = 0; k < 256; ++k) s = fmaf(xs[rl][k], wsh[k * 16 + p], s);
    #pragma unroll
    for (int off = 8; off; off >>= 1) s = fmaxf(s, __shfl_xor(s, off));
    if (p == 0) ent[m0 + rl] = s;
}

// ---------------------------------------------------------------------------
// argmax over T per batch (first-occurrence ties), write float index,
// gather U row into us/ue
// ---------------------------------------------------------------------------
__global__ void argmax_kernel(const float* __restrict__ sc, const float* __restrict__ U,
                              float* __restrict__ uvec, float* __restrict__ outidx)
{
    int b = blockIdx.x;
    int tid = threadIdx.x;  // 256
    float bv = -3.4e38f;
    int bi = 0x7fffffff;
    for (int t = tid; t < cT; t += 256) {
        float v = sc[b * cT + t];
        if (v > bv || (v == bv && t < bi)) { bv = v; bi = t; }
    }
    __shared__ float vs[256];
    __shared__ int   is[256];
    vs[tid] = bv; is[tid] = bi;
    __syncthreads();
    for (int s = 128; s > 0; s >>= 1) {
        if (tid < s) {
            if (vs[tid + s] > vs[tid] ||
                (vs[tid + s] == vs[tid] && is[tid + s] < is[tid])) {
                vs[tid] = vs[tid + s];
                is[tid] = is[tid + s];
            }
        }
        __syncthreads();
    }
    int best = is[0];
    if (tid == 0) outidx[b] = (float)best;
    uvec[b * cD + tid % cD] = U[((size_t)b * cT + best) * cD + (tid % cD)];
}

// ---------------------------------------------------------------------------
// LSTM cell
// ---------------------------------------------------------------------------
__global__ void lstm_kernel(const float* __restrict__ us, const float* __restrict__ ue,
                            float* __restrict__ h, float* __restrict__ c,
                            const float* __restrict__ wih, const float* __restrict__ whh,
                            const float* __restrict__ bih, const float* __restrict__ bhh)
{
    int b = blockIdx.x;
    int j = threadIdx.x;  // 128
    __shared__ float x[512];
    __shared__ float hh[128];
    x[j]       = us[b * cD + j];
    x[128 + j] = us[b * cD + 128 + j];
    x[256 + j] = ue[b * cD + j];
    x[384 + j] = ue[b * cD + 128 + j];
    hh[j] = h[b * cH + j];
    __syncthreads();
    float g4[4];
    #pragma unroll
    for (int gi = 0; gi < 4; ++gi) {
        int row = gi * 128 + j;
        float s = bih[row] + bhh[row];
        const float* wr = wih + (size_t)row * 512;
        for (int k = 0; k < 512; ++k) s = fmaf(x[k], wr[k], s);
        const float* wr2 = whh + (size_t)row * 128;
        for (int k = 0; k < 128; ++k) s = fmaf(hh[k], wr2[k], s);
        g4[gi] = s;
    }
    float i_ = 1.f / (1.f + expf(-g4[0]));
    float f_ = 1.f / (1.f + expf(-g4[1]));
    float g_ = tanhf(g4[2]);
    float o_ = 1.f / (1.f + expf(-g4[3]));
    float c2 = f_ * c[b * cH + j] + i_ * g_;
    float h2 = o_ * tanhf(c2);
    c[b * cH + j] = c2;
    h[b * cH + j] = h2;
}

__global__ void init_kernel(const float* __restrict__ U, float* __restrict__ us,
                            float* __restrict__ ue, float* __restrict__ h,
                            float* __restrict__ c)
{
    int i = blockIdx.x * 256 + threadIdx.x;  // 8192 threads
    if (i < cB * cD) {
        int b = i >> 8, d = i & 255;
        us[i] = U[((size_t)b * cT + 0) * cD + d];
        ue[i] = U[((size_t)b * cT + 1) * cD + d];
    }
    if (i < cB * cH) { h[i] = 0.f; c[i] = 0.f; }
}

// ---------------------------------------------------------------------------
extern "C" void kernel_launch(void* const* d_in, const int* in_sizes, int n_in,
                              void* d_out, int out_size, void* d_ws, size_t ws_size,
                              hipStream_t stream)
{
    const float* U = (const float*)d_in[0];
    const float* WD_w[2] = {(const float*)d_in[1], (const float*)d_in[9]};
    const float* WD_b[2] = {(const float*)d_in[2], (const float*)d_in[10]};
    const float* W1_w[2] = {(const float*)d_in[3], (const float*)d_in[11]};
    const float* W1_b[2] = {(const float*)d_in[4], (const float*)d_in[12]};
    const float* W2_w[2] = {(const float*)d_in[5], (const float*)d_in[13]};
    const float* W2_b[2] = {(const float*)d_in[6], (const float*)d_in[14]};
    const float* W3_w[2] = {(const float*)d_in[7], (const float*)d_in[15]};
    const float* W3_b[2] = {(const float*)d_in[8], (const float*)d_in[16]};
    const float* wih = (const float*)d_in[17];
    const float* whh = (const float*)d_in[18];
    const float* bih = (const float*)d_in[19];
    const float* bhh = (const float*)d_in[20];

    float* ws = (float*)d_ws;
    float* m1 = ws;                               // 4M floats
    float* m2 = m1 + (size_t)cM * cH;             // 4M
    float* us = m2 + (size_t)cM * cH;
    float* ue = us + cB * cD;
    float* h  = ue + cB * cD;
    float* c  = h + cB * cH;
    float* r  = c + cB * cH;
    float* rterm = r + cB * cH;                   // 64K
    float* cur = rterm + (size_t)cB * cN;

    ushort* m1h = (ushort*)cur;                   cur += (size_t)cM * cH / 2;
    ushort* m1l = (ushort*)cur;                   cur += (size_t)cM * cH / 2;
    ushort* Uh  = (ushort*)cur;                   cur += (size_t)cM * cD / 2;
    ushort* Ul  = (ushort*)cur;                   cur += (size_t)cM * cD / 2;
    ushort* W1th[2], *W1tl[2], *W2th[2], *W2tl[2];
    for (int sd = 0; sd < 2; ++sd) {
        W1th[sd] = (ushort*)cur; cur += (size_t)cN * cD / 2;   // [2048][256]
        W1tl[sd] = (ushort*)cur; cur += (size_t)cN * cD / 2;
        W2th[sd] = (ushort*)cur; cur += (size_t)cN * cH / 2;   // [2048][128]
        W2tl[sd] = (ushort*)cur; cur += (size_t)cN * cH / 2;
    }

    float* outf = (float*)d_out;

    init_kernel<<<32, 256, 0, stream>>>(U, us, ue, h, c);
    usplit_kernel<<<(cM * cD) / 256, 256, 0, stream>>>(U, Uh, Ul);
    for (int sd = 0; sd < 2; ++sd) {
        wsplit_kernel<<<(cD * cN) / 256, 256, 0, stream>>>(
            W1_w[sd], cD, cN, W1th[sd], W1tl[sd]);     // first 256 rows of W1
        wsplit_kernel<<<(cH * cN) / 256, 256, 0, stream>>>(
            W2_w[sd], cH, cN, W2th[sd], W2tl[sd]);
    }

    const int ggrid = (cN / 128) * (cM / 128);   // 4096 (fused m1 grid)
    for (int it = 0; it < 4; ++it) {
        for (int sd = 0; sd < 2; ++sd) {
            r_kernel<<<32, 128, 0, stream>>>(h, us, ue, WD_w[sd], WD_b[sd], r);
            rterm_kernel<<<dim3(8, 32), 256, 0, stream>>>(
                r, W1_w[sd] + (size_t)256 * cN, W1_b[sd], rterm);
            // m1 = pool(U @ W1[0:256] + rterm) -> fp32 + bf16 hi/lo (fused)
            mfma_pool_swp<256, true><<<ggrid, 256, 0, stream>>>(
                W1th[sd], W1tl[sd], Uh, Ul, rterm, cN, m1, m1h, m1l);
            // m2 = pool(m1 @ W2 + b2) -> fp32 (multi-subtile S=4)
            mfma_pool_m2<<<1024, 256, 0, stream>>>(
                W2th[sd], W2tl[sd], m1h, m1l, W2_b[sd], m2);
            float* ent = outf + 64 + (size_t)(it * 2 + sd) * cB * cT;
            score_kernel<<<2048, 256, 0, stream>>>(m1, m2, W3_w[sd], W3_b[sd], ent);
            argmax_kernel<<<32, 256, 0, stream>>>(ent, U, sd ? ue : us,
                                                  outf + (sd ? 32 : 0));
        }
        lstm_kernel<<<32, 128, 0, stream>>>(us, ue, h, c, wih, whh, bih, bhh);
    }
}